// Round 1
// baseline (6435.449 us; speedup 1.0000x reference)
//
#include <hip/hip_runtime.h>
#include <hip/hip_bf16.h>
#include <cstdint>
#include <cstddef>

// Problem constants (from reference)
#define NNODES 50000
#define NGRAPHS 64

// ---------------- degree / norm ----------------
__global__ void deg_count_k(const int* __restrict__ col, int* __restrict__ cnt, int ne) {
    int i = blockIdx.x * blockDim.x + threadIdx.x;
    if (i < ne) atomicAdd(&cnt[col[i]], 1);
}

__global__ void dinv_k(const int* __restrict__ cnt, float* __restrict__ dinv, int n) {
    int i = blockIdx.x * blockDim.x + threadIdx.x;
    if (i < n) dinv[i] = rsqrtf((float)(cnt[i] + 1));
}

// ---------------- aggregation ----------------
// out[r][f] = dinv[r]^2 * in[r][f] (+ bias[f])   (self-loop term + bias init)
template<int F>
__global__ void agg_init_k(const float* __restrict__ in, const float* __restrict__ dinv,
                           const float* __restrict__ bias, float* __restrict__ out, int n) {
    long long idx = (long long)blockIdx.x * blockDim.x + threadIdx.x;
    long long total = (long long)n * F;
    if (idx >= total) return;
    int r = (int)(idx >> __builtin_ctz(F));
    int f = (int)(idx & (F - 1));
    float d = dinv[r];
    float v = d * d * in[idx];
    if (bias) v += bias[f];
    out[idx] = v;
}

// out[col[e]][f] += dinv[row]*dinv[col] * in[row[e]][f]   (float4 per thread)
template<int F>
__global__ void agg_edges_k(const float* __restrict__ in, const int* __restrict__ row_,
                            const int* __restrict__ col_, const float* __restrict__ dinv,
                            float* __restrict__ out, int ne) {
    constexpr int FV = F / 4;
    long long idx = (long long)blockIdx.x * blockDim.x + threadIdx.x;
    long long total = (long long)ne * FV;
    if (idx >= total) return;
    int e  = (int)(idx / FV);
    int fv = (int)(idx & (FV - 1));
    int r = row_[e], c = col_[e];
    float nrm = dinv[r] * dinv[c];
    float4 v = *reinterpret_cast<const float4*>(&in[(size_t)r * F + fv * 4]);
    float* op = &out[(size_t)c * F + fv * 4];
    atomicAdd(op + 0, nrm * v.x);
    atomicAdd(op + 1, nrm * v.y);
    atomicAdd(op + 2, nrm * v.z);
    atomicAdd(op + 3, nrm * v.w);
}

// ---------------- batchnorm ----------------
__global__ void bn_stats_k(const float* __restrict__ in, float* __restrict__ sums,
                           float* __restrict__ sqs, int n, int F) {
    int f = blockIdx.x * blockDim.x + threadIdx.x;
    if (f >= F) return;
    float s = 0.f, q = 0.f;
    for (int r = blockIdx.y; r < n; r += gridDim.y) {
        float v = in[(size_t)r * F + f];
        s += v; q += v * v;
    }
    atomicAdd(&sums[f], s);
    atomicAdd(&sqs[f], q);
}

__global__ void bn_finalize_k(const float* __restrict__ sums, const float* __restrict__ sqs,
                              const float* __restrict__ g, const float* __restrict__ be,
                              float* __restrict__ scale, float* __restrict__ shift,
                              int F, float invn) {
    int f = blockIdx.x * blockDim.x + threadIdx.x;
    if (f >= F) return;
    float mean = sums[f] * invn;
    float var  = sqs[f] * invn - mean * mean;
    float rstd = rsqrtf(var + 1e-5f);
    float sc = g[f] * rstd;
    scale[f] = sc;
    shift[f] = be[f] - mean * sc;
}

__global__ void bn_apply_k(float* __restrict__ x, const float* __restrict__ scale,
                           const float* __restrict__ shift, long long total, int fmask) {
    long long idx = (long long)blockIdx.x * blockDim.x + threadIdx.x;
    if (idx >= total) return;
    int f = (int)(idx & fmask);
    float v = x[idx] * scale[f] + shift[f];
    x[idx] = fmaxf(v, 0.f);
}

// ---------------- GEMM: C[n,M] = A[n,K] @ W[K,M] (+bias) ----------------
// BM=BN=64, BK=16, 256 threads, 4x4 micro-tile per thread. fp32 VALU.
template<bool HAS_BIAS>
__global__ __launch_bounds__(256) void gemm_k(const float* __restrict__ A,
                                              const float* __restrict__ W,
                                              const float* __restrict__ bias,
                                              float* __restrict__ C,
                                              int n, int K, int M) {
    __shared__ float As[16][64];  // [k][row]
    __shared__ float Ws[16][64];  // [k][col]
    int bx = blockIdx.x, by = blockIdx.y;
    int tid = threadIdx.x;
    int tx = tid & 15, ty = tid >> 4;
    int row0 = by * 64;
    float acc[4][4] = {};

    for (int kt = 0; kt < K; kt += 16) {
        { // load A tile 64x16 (transposed into LDS)
            int r  = tid >> 2;
            int c4 = (tid & 3) * 4;
            int gr = row0 + r;
            float4 v = make_float4(0.f, 0.f, 0.f, 0.f);
            if (gr < n) v = *reinterpret_cast<const float4*>(&A[(size_t)gr * K + kt + c4]);
            As[c4 + 0][r] = v.x; As[c4 + 1][r] = v.y;
            As[c4 + 2][r] = v.z; As[c4 + 3][r] = v.w;
        }
        { // load W tile 16x64
            int r  = tid >> 4;
            int c4 = (tid & 15) * 4;
            float4 v = *reinterpret_cast<const float4*>(&W[(size_t)(kt + r) * M + bx * 64 + c4]);
            *reinterpret_cast<float4*>(&Ws[r][c4]) = v;
        }
        __syncthreads();
        #pragma unroll
        for (int kk = 0; kk < 16; ++kk) {
            float a[4], w[4];
            #pragma unroll
            for (int i = 0; i < 4; ++i) a[i] = As[kk][ty * 4 + i];
            #pragma unroll
            for (int j = 0; j < 4; ++j) w[j] = Ws[kk][tx * 4 + j];
            #pragma unroll
            for (int i = 0; i < 4; ++i)
                #pragma unroll
                for (int j = 0; j < 4; ++j)
                    acc[i][j] += a[i] * w[j];
        }
        __syncthreads();
    }

    #pragma unroll
    for (int i = 0; i < 4; ++i) {
        int gr = row0 + ty * 4 + i;
        if (gr < n) {
            int gc = bx * 64 + tx * 4;
            float4 v = make_float4(acc[i][0], acc[i][1], acc[i][2], acc[i][3]);
            if (HAS_BIAS) {
                v.x += bias[gc + 0]; v.y += bias[gc + 1];
                v.z += bias[gc + 2]; v.w += bias[gc + 3];
            }
            *reinterpret_cast<float4*>(&C[(size_t)gr * M + gc]) = v;
        }
    }
}

// ---------------- pooling + output ----------------
__global__ void pool_sum_k(const float* __restrict__ a, const int* __restrict__ batch,
                           float* __restrict__ sums, int* __restrict__ cnt, int n) {
    long long idx = (long long)blockIdx.x * blockDim.x + threadIdx.x;
    long long total = (long long)n * 128;
    if (idx >= total) return;
    int r = (int)(idx >> 7), f = (int)(idx & 127);
    int g = batch[r];
    atomicAdd(&sums[g * 128 + f], a[idx]);
    if (f == 0) atomicAdd(&cnt[g], 1);
}

__global__ void final_out_k(const float* __restrict__ sums, const int* __restrict__ cnt,
                            const float* __restrict__ Wo, const float* __restrict__ bo,
                            float* __restrict__ out) {
    int idx = blockIdx.x * blockDim.x + threadIdx.x;
    if (idx >= NGRAPHS * 10) return;
    int g = idx / 10, c = idx - g * 10;
    float inv = 1.0f / fmaxf((float)cnt[g], 1.0f);
    float s = bo[c];
    for (int k = 0; k < 128; ++k)
        s += sums[g * 128 + k] * inv * Wo[k * 10 + c];
    out[idx] = s;
}

// ---------------- driver ----------------
extern "C" void kernel_launch(void* const* d_in, const int* in_sizes, int n_in,
                              void* d_out, int out_size, void* d_ws, size_t ws_size,
                              hipStream_t stream) {
    const float* x   = (const float*)d_in[0];
    const int*   ei  = (const int*)d_in[1];
    const int*   bat = (const int*)d_in[2];
    const float* W1  = (const float*)d_in[3];
    const float* b1  = (const float*)d_in[4];
    const float* g1  = (const float*)d_in[5];
    const float* be1 = (const float*)d_in[6];
    const float* W2  = (const float*)d_in[7];
    const float* b2  = (const float*)d_in[8];
    const float* g2  = (const float*)d_in[9];
    const float* be2 = (const float*)d_in[10];
    const float* W3  = (const float*)d_in[11];
    const float* b3  = (const float*)d_in[12];
    const float* g3  = (const float*)d_in[13];
    const float* be3 = (const float*)d_in[14];
    const float* Wo  = (const float*)d_in[15];
    const float* bo  = (const float*)d_in[16];
    float* out = (float*)d_out;

    const int n  = in_sizes[2];       // 50000 nodes
    const int ne = in_sizes[1] / 2;   // 800000 edges
    const int* row = ei;
    const int* col = ei + ne;

    float* ws = (float*)d_ws;
    size_t o = 0;
    int*   cnt  = (int*)(ws + o); o += 50048;
    float* dinv = ws + o;         o += 50048;
    float* bufA = ws + o;         o += (size_t)NNODES * 512;   // h1/a1 ; later h2/a2 (alias)
    float* bufB = ws + o;         o += (size_t)NNODES * 256;   // t2 ; later h3/a3
    float* bufD = ws + o;         o += (size_t)NNODES * 128;   // Ax ; later t3
    float* sums  = ws + o; o += 512;
    float* sqs   = ws + o; o += 512;
    float* scale = ws + o; o += 512;
    float* shift = ws + o; o += 512;
    float* psum  = ws + o; o += NGRAPHS * 128;
    int*   pcnt  = (int*)(ws + o); o += 64;
    float* bufC = bufA;  // alias: a1 dead once t2 exists

    auto bn = [&](float* buf, int F, const float* g, const float* be) {
        hipMemsetAsync(sums, 0, F * sizeof(float), stream);
        hipMemsetAsync(sqs,  0, F * sizeof(float), stream);
        dim3 gs((F + 255) / 256, 256);
        bn_stats_k<<<gs, 256, 0, stream>>>(buf, sums, sqs, n, F);
        bn_finalize_k<<<(F + 255) / 256, 256, 0, stream>>>(sums, sqs, g, be, scale, shift, F, 1.0f / n);
        long long total = (long long)n * F;
        bn_apply_k<<<(unsigned)((total + 255) / 256), 256, 0, stream>>>(buf, scale, shift, total, F - 1);
    };

    // degrees
    hipMemsetAsync(cnt, 0, n * sizeof(int), stream);
    deg_count_k<<<(ne + 255) / 256, 256, 0, stream>>>(col, cnt, ne);
    dinv_k<<<(n + 255) / 256, 256, 0, stream>>>(cnt, dinv, n);

    // ---- Layer 1: agg(x) [128] -> @W1+b1 [512] -> BN+ReLU ----
    agg_init_k<128><<<(unsigned)(((long long)n * 128 + 255) / 256), 256, 0, stream>>>(x, dinv, nullptr, bufD, n);
    agg_edges_k<128><<<(unsigned)(((long long)ne * 32 + 255) / 256), 256, 0, stream>>>(x, row, col, dinv, bufD, ne);
    gemm_k<true><<<dim3(512 / 64, (n + 63) / 64), 256, 0, stream>>>(bufD, W1, b1, bufA, n, 128, 512);
    bn(bufA, 512, g1, be1);

    // ---- Layer 2: @W2 [256] -> agg + b2 -> BN+ReLU ----
    gemm_k<false><<<dim3(256 / 64, (n + 63) / 64), 256, 0, stream>>>(bufA, W2, nullptr, bufB, n, 512, 256);
    agg_init_k<256><<<(unsigned)(((long long)n * 256 + 255) / 256), 256, 0, stream>>>(bufB, dinv, b2, bufC, n);
    agg_edges_k<256><<<(unsigned)(((long long)ne * 64 + 255) / 256), 256, 0, stream>>>(bufB, row, col, dinv, bufC, ne);
    bn(bufC, 256, g2, be2);

    // ---- Layer 3: @W3 [128] -> agg + b3 -> BN+ReLU ----
    gemm_k<false><<<dim3(128 / 64, (n + 63) / 64), 256, 0, stream>>>(bufC, W3, nullptr, bufD, n, 256, 128);
    agg_init_k<128><<<(unsigned)(((long long)n * 128 + 255) / 256), 256, 0, stream>>>(bufD, dinv, b3, bufB, n);
    agg_edges_k<128><<<(unsigned)(((long long)ne * 32 + 255) / 256), 256, 0, stream>>>(bufD, row, col, dinv, bufB, ne);
    bn(bufB, 128, g3, be3);

    // ---- pool + output ----
    hipMemsetAsync(psum, 0, NGRAPHS * 128 * sizeof(float), stream);
    hipMemsetAsync(pcnt, 0, NGRAPHS * sizeof(int), stream);
    pool_sum_k<<<(unsigned)(((long long)n * 128 + 255) / 256), 256, 0, stream>>>(bufB, bat, psum, pcnt, n);
    final_out_k<<<3, 256, 0, stream>>>(psum, pcnt, Wo, bo, out);
}

// Round 2
// 1007.937 us; speedup vs baseline: 6.3848x; 6.3848x over previous
//
#include <hip/hip_runtime.h>
#include <hip/hip_bf16.h>
#include <cstdint>
#include <cstddef>

#define NNODES 50000
#define NGRAPHS 64

typedef short bf16x8 __attribute__((ext_vector_type(8)));
typedef float f32x4 __attribute__((ext_vector_type(4)));

__device__ inline float bf2f(unsigned short u) {
    return __uint_as_float(((unsigned)u) << 16);
}
__device__ inline unsigned short f2bf(float f) {
    unsigned u = __float_as_uint(f);
    unsigned r = (u + 0x7fff + ((u >> 16) & 1)) >> 16;  // RNE
    return (unsigned short)r;
}

// ---------------- degree / norm ----------------
__global__ void deg_count_k(const int* __restrict__ col, int* __restrict__ cnt, int ne) {
    int i = blockIdx.x * blockDim.x + threadIdx.x;
    if (i < ne) atomicAdd(&cnt[col[i]], 1);
}

__global__ void dinv_k(const int* __restrict__ cnt, float* __restrict__ dinv, int n) {
    int i = blockIdx.x * blockDim.x + threadIdx.x;
    if (i < n) dinv[i] = rsqrtf((float)(cnt[i] + 1));
}

// ---------------- exclusive scan (single block, 1024 threads) ----------------
__global__ __launch_bounds__(1024) void scan_k(const int* __restrict__ cnt, int* __restrict__ offs, int n) {
    __shared__ int part[1024];
    int t = threadIdx.x;
    int chunk = (n + 1023) / 1024;
    int lo = t * chunk, hi = min(n, lo + chunk);
    int s = 0;
    for (int i = lo; i < hi; ++i) s += cnt[i];
    part[t] = s;
    __syncthreads();
    for (int d = 1; d < 1024; d <<= 1) {
        int v = 0;
        if (t >= d) v = part[t - d];
        __syncthreads();
        part[t] += v;
        __syncthreads();
    }
    int excl = (t == 0) ? 0 : part[t - 1];
    for (int i = lo; i < hi; ++i) { offs[i] = excl; excl += cnt[i]; }
}

// ---------------- CSR scatter ----------------
__global__ void scatter_k(const int* __restrict__ row_, const int* __restrict__ col_,
                          const float* __restrict__ dinv, const int* __restrict__ offs,
                          int* __restrict__ fill, int* __restrict__ csr_row,
                          float* __restrict__ csr_nrm, int ne) {
    int e = blockIdx.x * blockDim.x + threadIdx.x;
    if (e >= ne) return;
    int r = row_[e], c = col_[e];
    int pos = offs[c] + atomicAdd(&fill[c], 1);
    csr_row[pos] = r;
    csr_nrm[pos] = dinv[r] * dinv[c];
}

// ---------------- fp32 -> bf16 conversion (4 elems/thread) ----------------
__global__ void cvt_bf_k(const float* __restrict__ in, unsigned short* __restrict__ out, long long total4) {
    long long i = (long long)blockIdx.x * blockDim.x + threadIdx.x;
    if (i >= total4) return;
    float4 v = reinterpret_cast<const float4*>(in)[i];
    uint2 o;
    o.x = (unsigned)f2bf(v.x) | ((unsigned)f2bf(v.y) << 16);
    o.y = (unsigned)f2bf(v.z) | ((unsigned)f2bf(v.w) << 16);
    reinterpret_cast<uint2*>(out)[i] = o;
}

// ---------------- weight transpose + convert: W[K][M] f32 -> Wt[M][K] bf16 ----------------
__global__ void wtrans_k(const float* __restrict__ W, unsigned short* __restrict__ Wt, int K, int M) {
    int idx = blockIdx.x * blockDim.x + threadIdx.x;
    if (idx >= K * M) return;
    int k = idx / M, m = idx - k * M;
    Wt[(size_t)m * K + k] = f2bf(W[idx]);
}

// ---------------- CSR aggregation: one wave per node ----------------
// out[c] = sum_{e in CSR[c]} nrm[e]*in[row[e]] + dinv[c]^2*in[c]
template<int FC>  // features per lane; F = 64*FC
__global__ void agg_csr_k(const unsigned short* __restrict__ in, const int* __restrict__ offs,
                          const int* __restrict__ cnt, const int* __restrict__ csr_row,
                          const float* __restrict__ csr_nrm, const float* __restrict__ dinv,
                          unsigned short* __restrict__ out, int n) {
    const int F = 64 * FC;
    int node = blockIdx.x * (blockDim.x >> 6) + (threadIdx.x >> 6);
    if (node >= n) return;
    int lane = threadIdx.x & 63;
    float acc[FC];
    #pragma unroll
    for (int i = 0; i < FC; ++i) acc[i] = 0.f;

    int s = offs[node], e1 = s + cnt[node];
    for (int e = s; e < e1; ++e) {
        int r = csr_row[e];
        float nm = csr_nrm[e];
        const unsigned short* p = in + (size_t)r * F + lane * FC;
        #pragma unroll
        for (int i = 0; i < FC; ++i) acc[i] += nm * bf2f(p[i]);
    }
    float dn = dinv[node];
    float nm = dn * dn;
    const unsigned short* p = in + (size_t)node * F + lane * FC;
    #pragma unroll
    for (int i = 0; i < FC; ++i) acc[i] += nm * bf2f(p[i]);

    unsigned short* q = out + (size_t)node * F + lane * FC;
    #pragma unroll
    for (int i = 0; i < FC; ++i) q[i] = f2bf(acc[i]);
}

// ---------------- bf16 MFMA GEMM: C[n][M] = A[n][K] @ B[M][K]^T ----------------
// 128x128 tile, BK=32, 4 waves (2x2 of 64x64), 16x16x32 mfma
__global__ __launch_bounds__(256) void gemm_bt_k(const unsigned short* __restrict__ A,
                                                 const unsigned short* __restrict__ B,
                                                 unsigned short* __restrict__ C,
                                                 int n, int K, int M) {
    __shared__ unsigned short As[128][40];  // 32 + 8 pad
    __shared__ unsigned short Bs[128][40];
    int tid = threadIdx.x;
    int wid = tid >> 6, lane = tid & 63;
    int wr = wid >> 1, wc = wid & 1;
    int row0 = blockIdx.y * 128, col0 = blockIdx.x * 128;

    f32x4 acc[4][4] = {};

    for (int kt = 0; kt < K; kt += 32) {
        #pragma unroll
        for (int h = 0; h < 2; ++h) {
            int r = (tid >> 2) + h * 64;
            int c8 = (tid & 3) * 8;
            int gr = row0 + r;
            bf16x8 va = {};
            if (gr < n) va = *reinterpret_cast<const bf16x8*>(A + (size_t)gr * K + kt + c8);
            *reinterpret_cast<bf16x8*>(&As[r][c8]) = va;
            bf16x8 vb = *reinterpret_cast<const bf16x8*>(B + (size_t)(col0 + r) * K + kt + c8);
            *reinterpret_cast<bf16x8*>(&Bs[r][c8]) = vb;
        }
        __syncthreads();

        bf16x8 af[4], bfr[4];
        int koff = (lane >> 4) * 8;
        #pragma unroll
        for (int f = 0; f < 4; ++f) {
            af[f]  = *reinterpret_cast<const bf16x8*>(&As[wr * 64 + f * 16 + (lane & 15)][koff]);
            bfr[f] = *reinterpret_cast<const bf16x8*>(&Bs[wc * 64 + f * 16 + (lane & 15)][koff]);
        }
        #pragma unroll
        for (int i = 0; i < 4; ++i)
            #pragma unroll
            for (int j = 0; j < 4; ++j)
                acc[i][j] = __builtin_amdgcn_mfma_f32_16x16x32_bf16(af[i], bfr[j], acc[i][j], 0, 0, 0);
        __syncthreads();
    }

    #pragma unroll
    for (int i = 0; i < 4; ++i) {
        #pragma unroll
        for (int q = 0; q < 4; ++q) {
            int gr = row0 + wr * 64 + i * 16 + (lane >> 4) * 4 + q;
            if (gr < n) {
                #pragma unroll
                for (int j = 0; j < 4; ++j) {
                    int gc = col0 + wc * 64 + j * 16 + (lane & 15);
                    C[(size_t)gr * M + gc] = f2bf(acc[i][j][q]);
                }
            }
        }
    }
}

// ---------------- batchnorm ----------------
__global__ void bn_stats_k(const unsigned short* __restrict__ in, float* __restrict__ sums,
                           float* __restrict__ sqs, int n, int F) {
    int f = blockIdx.x * blockDim.x + threadIdx.x;
    if (f >= F) return;
    float s = 0.f, q = 0.f;
    for (int r = blockIdx.y; r < n; r += gridDim.y) {
        float v = bf2f(in[(size_t)r * F + f]);
        s += v; q += v * v;
    }
    atomicAdd(&sums[f], s);
    atomicAdd(&sqs[f], q);
}

__global__ void bn_finalize_k(const float* __restrict__ sums, const float* __restrict__ sqs,
                              const float* __restrict__ g, const float* __restrict__ be,
                              float* __restrict__ scale, float* __restrict__ shift,
                              int F, float invn) {
    int f = blockIdx.x * blockDim.x + threadIdx.x;
    if (f >= F) return;
    float mean = sums[f] * invn;
    float var  = sqs[f] * invn - mean * mean;
    float rstd = rsqrtf(var + 1e-5f);
    float sc = g[f] * rstd;
    scale[f] = sc;
    shift[f] = be[f] - mean * sc;
}

// in-place BN + ReLU on bf16, 4 elems/thread
__global__ void bn_apply_k(unsigned short* __restrict__ x, const float* __restrict__ scale,
                           const float* __restrict__ shift, long long total4, int fmask) {
    long long i = (long long)blockIdx.x * blockDim.x + threadIdx.x;
    if (i >= total4) return;
    uint2 v = reinterpret_cast<uint2*>(x)[i];
    int fb = (int)((i * 4) & fmask);
    float r0 = fmaxf(bf2f((unsigned short)(v.x & 0xffff))  * scale[fb + 0] + shift[fb + 0], 0.f);
    float r1 = fmaxf(bf2f((unsigned short)(v.x >> 16))     * scale[fb + 1] + shift[fb + 1], 0.f);
    float r2 = fmaxf(bf2f((unsigned short)(v.y & 0xffff))  * scale[fb + 2] + shift[fb + 2], 0.f);
    float r3 = fmaxf(bf2f((unsigned short)(v.y >> 16))     * scale[fb + 3] + shift[fb + 3], 0.f);
    uint2 o;
    o.x = (unsigned)f2bf(r0) | ((unsigned)f2bf(r1) << 16);
    o.y = (unsigned)f2bf(r2) | ((unsigned)f2bf(r3) << 16);
    reinterpret_cast<uint2*>(x)[i] = o;
}

// ---------------- pooling ----------------
__global__ void bounds_k(const int* __restrict__ batch, int* __restrict__ start, int n) {
    int i = blockIdx.x * blockDim.x + threadIdx.x;
    if (i >= n) return;
    int b = batch[i];
    if (i == 0) {
        for (int g = 0; g <= b; ++g) start[g] = 0;
    } else {
        int pb = batch[i - 1];
        for (int g = pb + 1; g <= b; ++g) start[g] = i;
    }
    if (i == n - 1) {
        for (int g = b + 1; g <= NGRAPHS; ++g) start[g] = n;
    }
}

__global__ void pool_k(const unsigned short* __restrict__ a, const int* __restrict__ start,
                       float* __restrict__ pooled) {
    int g = blockIdx.x;
    int f = threadIdx.x;  // 128 threads
    int s = start[g], e = start[g + 1];
    float sum = 0.f;
    for (int r = s; r < e; ++r) sum += bf2f(a[(size_t)r * 128 + f]);
    float c = (float)(e - s);
    pooled[g * 128 + f] = sum / fmaxf(c, 1.f);
}

__global__ void final_out_k(const float* __restrict__ pooled, const float* __restrict__ Wo,
                            const float* __restrict__ bo, float* __restrict__ out) {
    int idx = blockIdx.x * blockDim.x + threadIdx.x;
    if (idx >= NGRAPHS * 10) return;
    int g = idx / 10, c = idx - g * 10;
    float s = bo[c];
    for (int k = 0; k < 128; ++k)
        s += pooled[g * 128 + k] * Wo[k * 10 + c];
    out[idx] = s;
}

// ---------------- driver ----------------
extern "C" void kernel_launch(void* const* d_in, const int* in_sizes, int n_in,
                              void* d_out, int out_size, void* d_ws, size_t ws_size,
                              hipStream_t stream) {
    const float* x   = (const float*)d_in[0];
    const int*   ei  = (const int*)d_in[1];
    const int*   bat = (const int*)d_in[2];
    const float* W1  = (const float*)d_in[3];
    const float* g1  = (const float*)d_in[5];
    const float* be1 = (const float*)d_in[6];
    const float* W2  = (const float*)d_in[7];
    const float* g2  = (const float*)d_in[9];
    const float* be2 = (const float*)d_in[10];
    const float* W3  = (const float*)d_in[11];
    const float* g3  = (const float*)d_in[13];
    const float* be3 = (const float*)d_in[14];
    const float* Wo  = (const float*)d_in[15];
    const float* bo  = (const float*)d_in[16];
    float* out = (float*)d_out;

    const int n  = in_sizes[2];       // 50000
    const int ne = in_sizes[1] / 2;   // 800000
    const int* row = ei;
    const int* col = ei + ne;

    char* base = (char*)d_ws;
    size_t o = 0;
    auto alloc = [&](size_t bytes) -> char* {
        char* p = base + o;
        o += (bytes + 255) & ~(size_t)255;
        return p;
    };
    int*   cnt   = (int*)alloc(n * 4);
    int*   offs  = (int*)alloc(n * 4);
    int*   fill  = (int*)alloc(n * 4);
    float* dinv  = (float*)alloc(n * 4);
    int*   start = (int*)alloc((NGRAPHS + 1) * 4);
    float* sums  = (float*)alloc(512 * 4);
    float* sqs   = (float*)alloc(512 * 4);
    float* scale = (float*)alloc(512 * 4);
    float* shift = (float*)alloc(512 * 4);
    float* pooled= (float*)alloc(NGRAPHS * 128 * 4);
    int*   csr_row = (int*)alloc((size_t)ne * 4);
    float* csr_nrm = (float*)alloc((size_t)ne * 4);
    unsigned short* Wt1 = (unsigned short*)alloc((size_t)128 * 512 * 2);
    unsigned short* Wt2 = (unsigned short*)alloc((size_t)512 * 256 * 2);
    unsigned short* Wt3 = (unsigned short*)alloc((size_t)256 * 128 * 2);
    unsigned short* x_bf  = (unsigned short*)alloc((size_t)n * 128 * 2);
    unsigned short* ax_bf = (unsigned short*)alloc((size_t)n * 128 * 2);
    unsigned short* h1_bf = (unsigned short*)alloc((size_t)n * 512 * 2);
    unsigned short* t2_bf = (unsigned short*)alloc((size_t)n * 256 * 2);
    unsigned short* a2_bf = (unsigned short*)alloc((size_t)n * 256 * 2);
    unsigned short* t3_bf = (unsigned short*)alloc((size_t)n * 128 * 2);
    unsigned short* a3_bf = (unsigned short*)alloc((size_t)n * 128 * 2);

    auto bn = [&](unsigned short* buf, int F, const float* g, const float* be) {
        hipMemsetAsync(sums, 0, F * sizeof(float), stream);
        hipMemsetAsync(sqs,  0, F * sizeof(float), stream);
        dim3 gs((F + 255) / 256, 256);
        bn_stats_k<<<gs, 256, 0, stream>>>(buf, sums, sqs, n, F);
        bn_finalize_k<<<(F + 255) / 256, 256, 0, stream>>>(sums, sqs, g, be, scale, shift, F, 1.0f / n);
        long long total4 = (long long)n * F / 4;
        bn_apply_k<<<(unsigned)((total4 + 255) / 256), 256, 0, stream>>>(buf, scale, shift, total4, F - 1);
    };

    // ---- graph preprocessing ----
    hipMemsetAsync(cnt, 0, n * sizeof(int), stream);
    deg_count_k<<<(ne + 255) / 256, 256, 0, stream>>>(col, cnt, ne);
    dinv_k<<<(n + 255) / 256, 256, 0, stream>>>(cnt, dinv, n);
    scan_k<<<1, 1024, 0, stream>>>(cnt, offs, n);
    hipMemsetAsync(fill, 0, n * sizeof(int), stream);
    scatter_k<<<(ne + 255) / 256, 256, 0, stream>>>(row, col, dinv, offs, fill, csr_row, csr_nrm, ne);
    bounds_k<<<(n + 255) / 256, 256, 0, stream>>>(bat, start, n);

    // ---- conversions ----
    cvt_bf_k<<<(unsigned)(((long long)n * 128 / 4 + 255) / 256), 256, 0, stream>>>(x, x_bf, (long long)n * 128 / 4);
    wtrans_k<<<(128 * 512 + 255) / 256, 256, 0, stream>>>(W1, Wt1, 128, 512);
    wtrans_k<<<(512 * 256 + 255) / 256, 256, 0, stream>>>(W2, Wt2, 512, 256);
    wtrans_k<<<(256 * 128 + 255) / 256, 256, 0, stream>>>(W3, Wt3, 256, 128);

    // ---- Layer 1: agg(x)[128] -> @W1 [512] -> BN+ReLU  (conv bias canceled by BN) ----
    agg_csr_k<2><<<(n + 3) / 4, 256, 0, stream>>>(x_bf, offs, cnt, csr_row, csr_nrm, dinv, ax_bf, n);
    gemm_bt_k<<<dim3(512 / 128, (n + 127) / 128), 256, 0, stream>>>(ax_bf, Wt1, h1_bf, n, 128, 512);
    bn(h1_bf, 512, g1, be1);

    // ---- Layer 2: @W2 [256] -> agg -> BN+ReLU ----
    gemm_bt_k<<<dim3(256 / 128, (n + 127) / 128), 256, 0, stream>>>(h1_bf, Wt2, t2_bf, n, 512, 256);
    agg_csr_k<4><<<(n + 3) / 4, 256, 0, stream>>>(t2_bf, offs, cnt, csr_row, csr_nrm, dinv, a2_bf, n);
    bn(a2_bf, 256, g2, be2);

    // ---- Layer 3: @W3 [128] -> agg -> BN+ReLU ----
    gemm_bt_k<<<dim3(128 / 128, (n + 127) / 128), 256, 0, stream>>>(a2_bf, Wt3, t3_bf, n, 256, 128);
    agg_csr_k<2><<<(n + 3) / 4, 256, 0, stream>>>(t3_bf, offs, cnt, csr_row, csr_nrm, dinv, a3_bf, n);
    bn(a3_bf, 128, g3, be3);

    // ---- pool + output ----
    pool_k<<<NGRAPHS, 128, 0, stream>>>(a3_bf, start, pooled);
    final_out_k<<<3, 256, 0, stream>>>(pooled, Wo, bo, out);
}

// Round 3
// 721.035 us; speedup vs baseline: 8.9253x; 1.3979x over previous
//
#include <hip/hip_runtime.h>
#include <hip/hip_bf16.h>
#include <cstdint>
#include <cstddef>

#define NNODES 50000
#define NGRAPHS 64

typedef short bf16x8 __attribute__((ext_vector_type(8)));
typedef float f32x4 __attribute__((ext_vector_type(4)));

__device__ inline float bf2f(unsigned short u) {
    return __uint_as_float(((unsigned)u) << 16);
}
__device__ inline unsigned short f2bf(float f) {
    unsigned u = __float_as_uint(f);
    return (unsigned short)((u + 0x7fff + ((u >> 16) & 1)) >> 16);  // RNE
}

// ---------------- degree / norm ----------------
__global__ void deg_count_k(const int* __restrict__ col, int* __restrict__ cnt, int ne) {
    int i = blockIdx.x * blockDim.x + threadIdx.x;
    if (i < ne) atomicAdd(&cnt[col[i]], 1);
}

__global__ void dinv_k(const int* __restrict__ cnt, float* __restrict__ dinv, int n) {
    int i = blockIdx.x * blockDim.x + threadIdx.x;
    if (i < n) dinv[i] = rsqrtf((float)(cnt[i] + 1));
}

// ---------------- exclusive scan (single block) ----------------
__global__ __launch_bounds__(1024) void scan_k(const int* __restrict__ cnt, int* __restrict__ offs, int n) {
    __shared__ int part[1024];
    int t = threadIdx.x;
    int chunk = (n + 1023) / 1024;
    int lo = t * chunk, hi = min(n, lo + chunk);
    int s = 0;
    for (int i = lo; i < hi; ++i) s += cnt[i];
    part[t] = s;
    __syncthreads();
    for (int d = 1; d < 1024; d <<= 1) {
        int v = 0;
        if (t >= d) v = part[t - d];
        __syncthreads();
        part[t] += v;
        __syncthreads();
    }
    int excl = (t == 0) ? 0 : part[t - 1];
    for (int i = lo; i < hi; ++i) { offs[i] = excl; excl += cnt[i]; }
}

// ---------------- CSR scatter (row indices only; norm folded into data) ----------------
__global__ void scatter_k(const int* __restrict__ row_, const int* __restrict__ col_,
                          const int* __restrict__ offs, int* __restrict__ fill,
                          int* __restrict__ csr_row, int ne) {
    int e = blockIdx.x * blockDim.x + threadIdx.x;
    if (e >= ne) return;
    int r = row_[e], c = col_[e];
    int pos = offs[c] + atomicAdd(&fill[c], 1);
    csr_row[pos] = r;
}

// ---------------- fp32 -> bf16 with per-row dinv prescale ----------------
__global__ void cvt_scale_k(const float* __restrict__ in, const float* __restrict__ dinv,
                            unsigned short* __restrict__ out, int n) {
    long long i = (long long)blockIdx.x * blockDim.x + threadIdx.x;
    long long total4 = (long long)n * 32;  // 128/4 per row
    if (i >= total4) return;
    int r = (int)(i >> 5);
    float d = dinv[r];
    float4 v = reinterpret_cast<const float4*>(in)[i];
    uint2 o;
    o.x = (unsigned)f2bf(v.x * d) | ((unsigned)f2bf(v.y * d) << 16);
    o.y = (unsigned)f2bf(v.z * d) | ((unsigned)f2bf(v.w * d) << 16);
    reinterpret_cast<uint2*>(out)[i] = o;
}

// ---------------- weight transpose + convert: W[K][M] f32 -> Wt[M][K] bf16 ----------------
__global__ void wtrans_k(const float* __restrict__ W, unsigned short* __restrict__ Wt, int K, int M) {
    int idx = blockIdx.x * blockDim.x + threadIdx.x;
    if (idx >= K * M) return;
    int k = idx / M, m = idx - k * M;
    Wt[(size_t)m * K + k] = f2bf(W[idx]);
}

// ---------------- row load helper ----------------
template<int FC>
__device__ inline void loadrow(const unsigned short* __restrict__ p, float* v) {
    if constexpr (FC == 2) {
        unsigned u = *reinterpret_cast<const unsigned*>(p);
        v[0] = bf2f((unsigned short)(u & 0xffff));
        v[1] = bf2f((unsigned short)(u >> 16));
    } else {
        uint2 u = *reinterpret_cast<const uint2*>(p);
        v[0] = bf2f((unsigned short)(u.x & 0xffff));
        v[1] = bf2f((unsigned short)(u.x >> 16));
        v[2] = bf2f((unsigned short)(u.y & 0xffff));
        v[3] = bf2f((unsigned short)(u.y >> 16));
    }
}

// ---------------- CSR aggregation: one wave per node, prescaled input ----------------
// out[c] = f2bf( dinv[c] * ( in[c] + sum_{e in CSR[c]} in[row[e]] ) )
template<int FC>  // features per lane; F = 64*FC
__global__ void agg_s_k(const unsigned short* __restrict__ in, const int* __restrict__ offs,
                        const int* __restrict__ cnt, const int* __restrict__ csr_row,
                        const float* __restrict__ dinv, unsigned short* __restrict__ out, int n) {
    const int F = 64 * FC;
    int node = blockIdx.x * (blockDim.x >> 6) + (threadIdx.x >> 6);
    if (node >= n) return;
    int lane = threadIdx.x & 63;
    const size_t foff = (size_t)lane * FC;

    float acc[FC];
    loadrow<FC>(in + (size_t)node * F + foff, acc);  // self term (prescaled)

    int s = offs[node], e1 = s + cnt[node];
    int e = s;
    for (; e + 2 <= e1; e += 2) {
        int r0 = csr_row[e], r1 = csr_row[e + 1];
        float v0[FC], v1[FC];
        loadrow<FC>(in + (size_t)r0 * F + foff, v0);
        loadrow<FC>(in + (size_t)r1 * F + foff, v1);
        #pragma unroll
        for (int i = 0; i < FC; ++i) acc[i] += v0[i] + v1[i];
    }
    if (e < e1) {
        int r0 = csr_row[e];
        float v0[FC];
        loadrow<FC>(in + (size_t)r0 * F + foff, v0);
        #pragma unroll
        for (int i = 0; i < FC; ++i) acc[i] += v0[i];
    }

    float d = dinv[node];
    unsigned short* q = out + (size_t)node * F + foff;
    if constexpr (FC == 2) {
        unsigned o = (unsigned)f2bf(acc[0] * d) | ((unsigned)f2bf(acc[1] * d) << 16);
        *reinterpret_cast<unsigned*>(q) = o;
    } else {
        uint2 o;
        o.x = (unsigned)f2bf(acc[0] * d) | ((unsigned)f2bf(acc[1] * d) << 16);
        o.y = (unsigned)f2bf(acc[2] * d) | ((unsigned)f2bf(acc[3] * d) << 16);
        *reinterpret_cast<uint2*>(q) = o;
    }
}

// ---------------- bf16 MFMA GEMM: C[n][M] = A'[n][K] @ B[M][K]^T ----------------
// BN_A: A'[r][k] = relu(A[r][k]*scale[k]+shift[k]); SCALE_OUT: C row *= dinv[row]
template<bool BN_A, bool SCALE_OUT>
__global__ __launch_bounds__(256) void gemm_bt_k(const unsigned short* __restrict__ A,
                                                 const unsigned short* __restrict__ B,
                                                 unsigned short* __restrict__ C,
                                                 const float* __restrict__ scale,
                                                 const float* __restrict__ shift,
                                                 const float* __restrict__ dinv,
                                                 int n, int K, int M) {
    __shared__ unsigned short As[128][40];  // 32 + 8 pad
    __shared__ unsigned short Bs[128][40];
    int tid = threadIdx.x;
    int wid = tid >> 6, lane = tid & 63;
    int wr = wid >> 1, wc = wid & 1;
    int row0 = blockIdx.y * 128, col0 = blockIdx.x * 128;

    f32x4 acc[4][4] = {};

    for (int kt = 0; kt < K; kt += 32) {
        int c8 = (tid & 3) * 8;
        float4 sc0, sc1, sh0, sh1;
        if (BN_A) {
            sc0 = *reinterpret_cast<const float4*>(scale + kt + c8);
            sc1 = *reinterpret_cast<const float4*>(scale + kt + c8 + 4);
            sh0 = *reinterpret_cast<const float4*>(shift + kt + c8);
            sh1 = *reinterpret_cast<const float4*>(shift + kt + c8 + 4);
        }
        #pragma unroll
        for (int h = 0; h < 2; ++h) {
            int r = (tid >> 2) + h * 64;
            int gr = row0 + r;
            bf16x8 va = {};
            if (gr < n) va = *reinterpret_cast<const bf16x8*>(A + (size_t)gr * K + kt + c8);
            if (BN_A) {
                const float* scp = &sc0.x;
                const float* shp = &sh0.x;
                #pragma unroll
                for (int t = 0; t < 8; ++t) {
                    float sct = (t < 4) ? (&sc0.x)[t] : (&sc1.x)[t - 4];
                    float sht = (t < 4) ? (&sh0.x)[t] : (&sh1.x)[t - 4];
                    float f = bf2f((unsigned short)va[t]);
                    va[t] = (short)f2bf(fmaxf(f * sct + sht, 0.f));
                }
                (void)scp; (void)shp;
            }
            *reinterpret_cast<bf16x8*>(&As[r][c8]) = va;
            bf16x8 vb = *reinterpret_cast<const bf16x8*>(B + (size_t)(col0 + r) * K + kt + c8);
            *reinterpret_cast<bf16x8*>(&Bs[r][c8]) = vb;
        }
        __syncthreads();

        bf16x8 af[4], bfr[4];
        int koff = (lane >> 4) * 8;
        #pragma unroll
        for (int f = 0; f < 4; ++f) {
            af[f]  = *reinterpret_cast<const bf16x8*>(&As[wr * 64 + f * 16 + (lane & 15)][koff]);
            bfr[f] = *reinterpret_cast<const bf16x8*>(&Bs[wc * 64 + f * 16 + (lane & 15)][koff]);
        }
        #pragma unroll
        for (int i = 0; i < 4; ++i)
            #pragma unroll
            for (int j = 0; j < 4; ++j)
                acc[i][j] = __builtin_amdgcn_mfma_f32_16x16x32_bf16(af[i], bfr[j], acc[i][j], 0, 0, 0);
        __syncthreads();
    }

    #pragma unroll
    for (int i = 0; i < 4; ++i) {
        #pragma unroll
        for (int q = 0; q < 4; ++q) {
            int gr = row0 + wr * 64 + i * 16 + (lane >> 4) * 4 + q;
            if (gr < n) {
                float dr = SCALE_OUT ? dinv[gr] : 1.0f;
                #pragma unroll
                for (int j = 0; j < 4; ++j) {
                    int gc = col0 + wc * 64 + j * 16 + (lane & 15);
                    C[(size_t)gr * M + gc] = f2bf(acc[i][j][q] * dr);
                }
            }
        }
    }
}

// ---------------- batchnorm stats ----------------
__global__ void bn_stats_k(const unsigned short* __restrict__ in, float* __restrict__ sums,
                           float* __restrict__ sqs, int n, int F) {
    int f = blockIdx.x * blockDim.x + threadIdx.x;
    if (f >= F) return;
    float s = 0.f, q = 0.f;
    for (int r = blockIdx.y; r < n; r += gridDim.y) {
        float v = bf2f(in[(size_t)r * F + f]);
        s += v; q += v * v;
    }
    atomicAdd(&sums[f], s);
    atomicAdd(&sqs[f], q);
}

__global__ void bn_finalize_k(const float* __restrict__ sums, const float* __restrict__ sqs,
                              const float* __restrict__ g, const float* __restrict__ be,
                              float* __restrict__ scale, float* __restrict__ shift,
                              int F, float invn) {
    int f = blockIdx.x * blockDim.x + threadIdx.x;
    if (f >= F) return;
    float mean = sums[f] * invn;
    float var  = sqs[f] * invn - mean * mean;
    float rstd = rsqrtf(var + 1e-5f);
    float sc = g[f] * rstd;
    scale[f] = sc;
    shift[f] = be[f] - mean * sc;
}

// ---------------- pooling (with fused layer-3 BN+ReLU) ----------------
__global__ void bounds_k(const int* __restrict__ batch, int* __restrict__ start, int n) {
    int i = blockIdx.x * blockDim.x + threadIdx.x;
    if (i >= n) return;
    int b = batch[i];
    if (i == 0) {
        for (int g = 0; g <= b; ++g) start[g] = 0;
    } else {
        int pb = batch[i - 1];
        for (int g = pb + 1; g <= b; ++g) start[g] = i;
    }
    if (i == n - 1) {
        for (int g = b + 1; g <= NGRAPHS; ++g) start[g] = n;
    }
}

// grid (NGRAPHS, 4) x 256 threads: 16 lanes/row-group x 8 feats, 16 rows in parallel
__global__ __launch_bounds__(256) void pool_part_k(const unsigned short* __restrict__ a,
                                                   const int* __restrict__ start,
                                                   const float* __restrict__ scale,
                                                   const float* __restrict__ shift,
                                                   float* __restrict__ partial) {
    int g = blockIdx.x, q = blockIdx.y;
    int s = start[g], e = start[g + 1];
    int nr = e - s;
    int c0 = s + (nr * q) / 4, c1 = s + (nr * (q + 1)) / 4;
    int tf = threadIdx.x & 15, tr = threadIdx.x >> 4;

    float sc[8], sh[8];
    #pragma unroll
    for (int i = 0; i < 8; ++i) { sc[i] = scale[tf * 8 + i]; sh[i] = shift[tf * 8 + i]; }

    float acc[8] = {};
    for (int r = c0 + tr; r < c1; r += 16) {
        uint4 u = *reinterpret_cast<const uint4*>(a + (size_t)r * 128 + tf * 8);
        float v[8];
        v[0] = bf2f((unsigned short)(u.x & 0xffff)); v[1] = bf2f((unsigned short)(u.x >> 16));
        v[2] = bf2f((unsigned short)(u.y & 0xffff)); v[3] = bf2f((unsigned short)(u.y >> 16));
        v[4] = bf2f((unsigned short)(u.z & 0xffff)); v[5] = bf2f((unsigned short)(u.z >> 16));
        v[6] = bf2f((unsigned short)(u.w & 0xffff)); v[7] = bf2f((unsigned short)(u.w >> 16));
        #pragma unroll
        for (int i = 0; i < 8; ++i) acc[i] += fmaxf(v[i] * sc[i] + sh[i], 0.f);
    }

    __shared__ float red[16][128];
    #pragma unroll
    for (int i = 0; i < 8; ++i) red[tr][tf * 8 + i] = acc[i];
    __syncthreads();
    int f = threadIdx.x;
    if (f < 128) {
        float s2 = 0.f;
        #pragma unroll
        for (int t = 0; t < 16; ++t) s2 += red[t][f];
        partial[((size_t)(g * 4 + q)) * 128 + f] = s2;
    }
}

__global__ void final_out_k(const float* __restrict__ partial, const int* __restrict__ start,
                            const float* __restrict__ Wo, const float* __restrict__ bo,
                            float* __restrict__ out) {
    int idx = blockIdx.x * blockDim.x + threadIdx.x;
    if (idx >= NGRAPHS * 10) return;
    int g = idx / 10, c = idx - g * 10;
    float cntf = (float)(start[g + 1] - start[g]);
    float inv = 1.0f / fmaxf(cntf, 1.0f);
    float s = bo[c];
    for (int k = 0; k < 128; ++k) {
        float pk = partial[(size_t)(g * 4 + 0) * 128 + k] + partial[(size_t)(g * 4 + 1) * 128 + k]
                 + partial[(size_t)(g * 4 + 2) * 128 + k] + partial[(size_t)(g * 4 + 3) * 128 + k];
        s += pk * inv * Wo[k * 10 + c];
    }
    out[idx] = s;
}

// ---------------- driver ----------------
extern "C" void kernel_launch(void* const* d_in, const int* in_sizes, int n_in,
                              void* d_out, int out_size, void* d_ws, size_t ws_size,
                              hipStream_t stream) {
    const float* x   = (const float*)d_in[0];
    const int*   ei  = (const int*)d_in[1];
    const int*   bat = (const int*)d_in[2];
    const float* W1  = (const float*)d_in[3];
    const float* g1  = (const float*)d_in[5];
    const float* be1 = (const float*)d_in[6];
    const float* W2  = (const float*)d_in[7];
    const float* g2  = (const float*)d_in[9];
    const float* be2 = (const float*)d_in[10];
    const float* W3  = (const float*)d_in[11];
    const float* g3  = (const float*)d_in[13];
    const float* be3 = (const float*)d_in[14];
    const float* Wo  = (const float*)d_in[15];
    const float* bo  = (const float*)d_in[16];
    float* out = (float*)d_out;

    const int n  = in_sizes[2];       // 50000
    const int ne = in_sizes[1] / 2;   // 800000
    const int* row = ei;
    const int* col = ei + ne;

    char* base = (char*)d_ws;
    size_t o = 0;
    auto alloc = [&](size_t bytes) -> char* {
        char* p = base + o;
        o += (bytes + 255) & ~(size_t)255;
        return p;
    };
    int*   cnt   = (int*)alloc(n * 4);
    int*   offs  = (int*)alloc(n * 4);
    int*   fill  = (int*)alloc(n * 4);
    float* dinv  = (float*)alloc(n * 4);
    int*   start = (int*)alloc((NGRAPHS + 1) * 4);
    float* sums  = (float*)alloc(512 * 4);
    float* sqs   = (float*)alloc(512 * 4);
    float* scale = (float*)alloc(512 * 4);
    float* shift = (float*)alloc(512 * 4);
    float* partial = (float*)alloc((size_t)NGRAPHS * 4 * 128 * 4);
    int*   csr_row = (int*)alloc((size_t)ne * 4);
    unsigned short* Wt1 = (unsigned short*)alloc((size_t)128 * 512 * 2);
    unsigned short* Wt2 = (unsigned short*)alloc((size_t)512 * 256 * 2);
    unsigned short* Wt3 = (unsigned short*)alloc((size_t)256 * 128 * 2);
    unsigned short* xs_bf  = (unsigned short*)alloc((size_t)n * 128 * 2);
    unsigned short* ax_bf  = (unsigned short*)alloc((size_t)n * 128 * 2);
    unsigned short* h1_bf  = (unsigned short*)alloc((size_t)n * 512 * 2);
    unsigned short* t2s_bf = (unsigned short*)alloc((size_t)n * 256 * 2);
    unsigned short* a2_bf  = (unsigned short*)alloc((size_t)n * 256 * 2);
    unsigned short* t3s_bf = (unsigned short*)alloc((size_t)n * 128 * 2);
    unsigned short* a3_bf  = (unsigned short*)alloc((size_t)n * 128 * 2);

    auto bn_stats = [&](unsigned short* buf, int F, const float* g, const float* be) {
        hipMemsetAsync(sums, 0, F * sizeof(float), stream);
        hipMemsetAsync(sqs,  0, F * sizeof(float), stream);
        dim3 gs((F + 255) / 256, 256);
        bn_stats_k<<<gs, 256, 0, stream>>>(buf, sums, sqs, n, F);
        bn_finalize_k<<<(F + 255) / 256, 256, 0, stream>>>(sums, sqs, g, be, scale, shift, F, 1.0f / n);
    };

    // ---- graph preprocessing ----
    hipMemsetAsync(cnt, 0, n * sizeof(int), stream);
    deg_count_k<<<(ne + 255) / 256, 256, 0, stream>>>(col, cnt, ne);
    dinv_k<<<(n + 255) / 256, 256, 0, stream>>>(cnt, dinv, n);
    scan_k<<<1, 1024, 0, stream>>>(cnt, offs, n);
    hipMemsetAsync(fill, 0, n * sizeof(int), stream);
    scatter_k<<<(ne + 255) / 256, 256, 0, stream>>>(row, col, offs, fill, csr_row, ne);
    bounds_k<<<(n + 255) / 256, 256, 0, stream>>>(bat, start, n);

    // ---- conversions ----
    cvt_scale_k<<<(unsigned)(((long long)n * 32 + 255) / 256), 256, 0, stream>>>(x, dinv, xs_bf, n);
    wtrans_k<<<(128 * 512 + 255) / 256, 256, 0, stream>>>(W1, Wt1, 128, 512);
    wtrans_k<<<(512 * 256 + 255) / 256, 256, 0, stream>>>(W2, Wt2, 512, 256);
    wtrans_k<<<(256 * 128 + 255) / 256, 256, 0, stream>>>(W3, Wt3, 256, 128);

    // ---- Layer 1: agg(xs)[128] -> @W1 [512] ----
    agg_s_k<2><<<(n + 3) / 4, 256, 0, stream>>>(xs_bf, offs, cnt, csr_row, dinv, ax_bf, n);
    gemm_bt_k<false, false><<<dim3(4, (n + 127) / 128), 256, 0, stream>>>(
        ax_bf, Wt1, h1_bf, nullptr, nullptr, nullptr, n, 128, 512);
    bn_stats(h1_bf, 512, g1, be1);

    // ---- Layer 2: bn+relu(h1) @ W2 [256] (output prescaled) -> agg ----
    gemm_bt_k<true, true><<<dim3(2, (n + 127) / 128), 256, 0, stream>>>(
        h1_bf, Wt2, t2s_bf, scale, shift, dinv, n, 512, 256);
    agg_s_k<4><<<(n + 3) / 4, 256, 0, stream>>>(t2s_bf, offs, cnt, csr_row, dinv, a2_bf, n);
    bn_stats(a2_bf, 256, g2, be2);

    // ---- Layer 3: bn+relu(a2) @ W3 [128] (output prescaled) -> agg ----
    gemm_bt_k<true, true><<<dim3(1, (n + 127) / 128), 256, 0, stream>>>(
        a2_bf, Wt3, t3s_bf, scale, shift, dinv, n, 256, 128);
    agg_s_k<2><<<(n + 3) / 4, 256, 0, stream>>>(t3s_bf, offs, cnt, csr_row, dinv, a3_bf, n);
    bn_stats(a3_bf, 128, g3, be3);

    // ---- pool (fused BN+ReLU) + output ----
    pool_part_k<<<dim3(NGRAPHS, 4), 256, 0, stream>>>(a3_bf, start, scale, shift, partial);
    final_out_k<<<3, 256, 0, stream>>>(partial, start, Wo, bo, out);
}

// Round 4
// 655.834 us; speedup vs baseline: 9.8126x; 1.0994x over previous
//
#include <hip/hip_runtime.h>
#include <hip/hip_bf16.h>
#include <cstdint>
#include <cstddef>

#define NNODES 50000
#define NGRAPHS 64

typedef short bf16x8 __attribute__((ext_vector_type(8)));
typedef float f32x4 __attribute__((ext_vector_type(4)));

__device__ inline float bf2f(unsigned short u) {
    return __uint_as_float(((unsigned)u) << 16);
}
__device__ inline unsigned short f2bf(float f) {
    unsigned u = __float_as_uint(f);
    return (unsigned short)((u + 0x7fff + ((u >> 16) & 1)) >> 16);  // RNE
}

// ---------------- degree ----------------
__global__ void deg_count_k(const int* __restrict__ col, int* __restrict__ cnt, int ne) {
    int i = blockIdx.x * blockDim.x + threadIdx.x;
    if (i < ne) atomicAdd(&cnt[col[i]], 1);
}

// ---------------- multi-block exclusive scan (1024 elems/block) + dinv ----------------
__global__ __launch_bounds__(256) void scan1_k(const int* __restrict__ cnt, int* __restrict__ offs,
                                               int* __restrict__ bsum, float* __restrict__ dinv, int n) {
    int t = threadIdx.x;
    int base = blockIdx.x * 1024 + t * 4;
    int4 v = {0, 0, 0, 0};
    if (base + 3 < n) v = *reinterpret_cast<const int4*>(cnt + base);
    else {
        if (base + 0 < n) v.x = cnt[base + 0];
        if (base + 1 < n) v.y = cnt[base + 1];
        if (base + 2 < n) v.z = cnt[base + 2];
    }
    if (base + 0 < n) dinv[base + 0] = rsqrtf((float)(v.x + 1));
    if (base + 1 < n) dinv[base + 1] = rsqrtf((float)(v.y + 1));
    if (base + 2 < n) dinv[base + 2] = rsqrtf((float)(v.z + 1));
    if (base + 3 < n) dinv[base + 3] = rsqrtf((float)(v.w + 1));

    int s = v.x + v.y + v.z + v.w;
    __shared__ int lds[256];
    lds[t] = s;
    __syncthreads();
    #pragma unroll
    for (int d = 1; d < 256; d <<= 1) {
        int u = (t >= d) ? lds[t - d] : 0;
        __syncthreads();
        lds[t] += u;
        __syncthreads();
    }
    int excl = lds[t] - s;
    if (t == 255) bsum[blockIdx.x] = lds[t];

    if (base + 3 < n) {
        int4 o;
        o.x = excl; o.y = excl + v.x; o.z = o.y + v.y; o.w = o.z + v.z;
        *reinterpret_cast<int4*>(offs + base) = o;
    } else {
        int e = excl;
        if (base + 0 < n) { offs[base + 0] = e; e += v.x; }
        if (base + 1 < n) { offs[base + 1] = e; e += v.y; }
        if (base + 2 < n) { offs[base + 2] = e; }
    }
}

__global__ __launch_bounds__(256) void scan2_k(int* __restrict__ bsum, int nb) {
    __shared__ int lds[256];
    int t = threadIdx.x;
    int v = (t < nb) ? bsum[t] : 0;
    lds[t] = v;
    __syncthreads();
    #pragma unroll
    for (int d = 1; d < 256; d <<= 1) {
        int u = (t >= d) ? lds[t - d] : 0;
        __syncthreads();
        lds[t] += u;
        __syncthreads();
    }
    if (t < nb) bsum[t] = lds[t] - v;  // exclusive
}

__global__ __launch_bounds__(256) void scan3_k(int* __restrict__ offs, const int* __restrict__ bsum, int n) {
    int base = blockIdx.x * 1024 + threadIdx.x * 4;
    int add = bsum[blockIdx.x];
    if (base + 3 < n) {
        int4 o = *reinterpret_cast<int4*>(offs + base);
        o.x += add; o.y += add; o.z += add; o.w += add;
        *reinterpret_cast<int4*>(offs + base) = o;
    } else {
        for (int k = 0; k < 4; ++k)
            if (base + k < n) offs[base + k] += add;
    }
}

// ---------------- CSR scatter ----------------
__global__ void scatter_k(const int* __restrict__ row_, const int* __restrict__ col_,
                          const int* __restrict__ offs, int* __restrict__ fill,
                          int* __restrict__ csr_row, int ne) {
    int e = blockIdx.x * blockDim.x + threadIdx.x;
    if (e >= ne) return;
    int r = row_[e], c = col_[e];
    int pos = offs[c] + atomicAdd(&fill[c], 1);
    csr_row[pos] = r;
}

// ---------------- fp32 -> bf16 with per-row dinv prescale ----------------
__global__ void cvt_scale_k(const float* __restrict__ in, const float* __restrict__ dinv,
                            unsigned short* __restrict__ out, int n) {
    long long i = (long long)blockIdx.x * blockDim.x + threadIdx.x;
    long long total4 = (long long)n * 32;
    if (i >= total4) return;
    int r = (int)(i >> 5);
    float d = dinv[r];
    float4 v = reinterpret_cast<const float4*>(in)[i];
    uint2 o;
    o.x = (unsigned)f2bf(v.x * d) | ((unsigned)f2bf(v.y * d) << 16);
    o.y = (unsigned)f2bf(v.z * d) | ((unsigned)f2bf(v.w * d) << 16);
    reinterpret_cast<uint2*>(out)[i] = o;
}

// ---------------- weight transpose + convert ----------------
__global__ void wtrans_k(const float* __restrict__ W, unsigned short* __restrict__ Wt, int K, int M) {
    int idx = blockIdx.x * blockDim.x + threadIdx.x;
    if (idx >= K * M) return;
    int k = idx / M, m = idx - k * M;
    Wt[(size_t)m * K + k] = f2bf(W[idx]);
}

// ---------------- row load helper ----------------
template<int FC>
__device__ inline void loadrow(const unsigned short* __restrict__ p, float* v) {
    if constexpr (FC == 2) {
        unsigned u = *reinterpret_cast<const unsigned*>(p);
        v[0] = bf2f((unsigned short)(u & 0xffff));
        v[1] = bf2f((unsigned short)(u >> 16));
    } else {
        uint2 u = *reinterpret_cast<const uint2*>(p);
        v[0] = bf2f((unsigned short)(u.x & 0xffff));
        v[1] = bf2f((unsigned short)(u.x >> 16));
        v[2] = bf2f((unsigned short)(u.y & 0xffff));
        v[3] = bf2f((unsigned short)(u.y >> 16));
    }
}

// ---------------- CSR aggregation: one wave per node, prescaled input ----------------
template<int FC>
__global__ void agg_s_k(const unsigned short* __restrict__ in, const int* __restrict__ offs,
                        const int* __restrict__ cnt, const int* __restrict__ csr_row,
                        const float* __restrict__ dinv, unsigned short* __restrict__ out, int n) {
    const int F = 64 * FC;
    int node = blockIdx.x * (blockDim.x >> 6) + (threadIdx.x >> 6);
    if (node >= n) return;
    int lane = threadIdx.x & 63;
    const size_t foff = (size_t)lane * FC;

    float acc[FC];
    loadrow<FC>(in + (size_t)node * F + foff, acc);  // self term

    int s = offs[node], e1 = s + cnt[node];
    int e = s;
    for (; e + 4 <= e1; e += 4) {
        int r0 = csr_row[e], r1 = csr_row[e + 1], r2 = csr_row[e + 2], r3 = csr_row[e + 3];
        float v0[FC], v1[FC], v2[FC], v3[FC];
        loadrow<FC>(in + (size_t)r0 * F + foff, v0);
        loadrow<FC>(in + (size_t)r1 * F + foff, v1);
        loadrow<FC>(in + (size_t)r2 * F + foff, v2);
        loadrow<FC>(in + (size_t)r3 * F + foff, v3);
        #pragma unroll
        for (int i = 0; i < FC; ++i) acc[i] += (v0[i] + v1[i]) + (v2[i] + v3[i]);
    }
    for (; e < e1; ++e) {
        int r0 = csr_row[e];
        float v0[FC];
        loadrow<FC>(in + (size_t)r0 * F + foff, v0);
        #pragma unroll
        for (int i = 0; i < FC; ++i) acc[i] += v0[i];
    }

    float d = dinv[node];
    unsigned short* q = out + (size_t)node * F + foff;
    if constexpr (FC == 2) {
        unsigned o = (unsigned)f2bf(acc[0] * d) | ((unsigned)f2bf(acc[1] * d) << 16);
        *reinterpret_cast<unsigned*>(q) = o;
    } else {
        uint2 o;
        o.x = (unsigned)f2bf(acc[0] * d) | ((unsigned)f2bf(acc[1] * d) << 16);
        o.y = (unsigned)f2bf(acc[2] * d) | ((unsigned)f2bf(acc[3] * d) << 16);
        *reinterpret_cast<uint2*>(q) = o;
    }
}

// ---------------- bf16 MFMA GEMM ----------------
// BN_A: A'[r][k]=relu(A*scale[k]+shift[k]); SCALE_OUT: row *= dinv; STATS: column sum/sq -> atomics
template<bool BN_A, bool SCALE_OUT, bool STATS>
__global__ __launch_bounds__(256) void gemm_bt_k(const unsigned short* __restrict__ A,
                                                 const unsigned short* __restrict__ B,
                                                 unsigned short* __restrict__ C,
                                                 const float* __restrict__ scale,
                                                 const float* __restrict__ shift,
                                                 const float* __restrict__ dinv,
                                                 float* __restrict__ sums,
                                                 float* __restrict__ sqs,
                                                 int n, int K, int M) {
    __shared__ unsigned short As[128][40];
    __shared__ unsigned short Bs[128][40];
    int tid = threadIdx.x;
    int wid = tid >> 6, lane = tid & 63;
    int wr = wid >> 1, wc = wid & 1;
    int row0 = blockIdx.y * 128, col0 = blockIdx.x * 128;

    f32x4 acc[4][4] = {};

    for (int kt = 0; kt < K; kt += 32) {
        int c8 = (tid & 3) * 8;
        float4 sc0, sc1, sh0, sh1;
        if (BN_A) {
            sc0 = *reinterpret_cast<const float4*>(scale + kt + c8);
            sc1 = *reinterpret_cast<const float4*>(scale + kt + c8 + 4);
            sh0 = *reinterpret_cast<const float4*>(shift + kt + c8);
            sh1 = *reinterpret_cast<const float4*>(shift + kt + c8 + 4);
        }
        #pragma unroll
        for (int h = 0; h < 2; ++h) {
            int r = (tid >> 2) + h * 64;
            int gr = row0 + r;
            bf16x8 va = {};
            if (gr < n) va = *reinterpret_cast<const bf16x8*>(A + (size_t)gr * K + kt + c8);
            if (BN_A) {
                #pragma unroll
                for (int t = 0; t < 8; ++t) {
                    float sct = (t < 4) ? (&sc0.x)[t] : (&sc1.x)[t - 4];
                    float sht = (t < 4) ? (&sh0.x)[t] : (&sh1.x)[t - 4];
                    float f = bf2f((unsigned short)va[t]);
                    va[t] = (short)f2bf(fmaxf(f * sct + sht, 0.f));
                }
            }
            *reinterpret_cast<bf16x8*>(&As[r][c8]) = va;
            bf16x8 vb = *reinterpret_cast<const bf16x8*>(B + (size_t)(col0 + r) * K + kt + c8);
            *reinterpret_cast<bf16x8*>(&Bs[r][c8]) = vb;
        }
        __syncthreads();

        bf16x8 af[4], bfr[4];
        int koff = (lane >> 4) * 8;
        #pragma unroll
        for (int f = 0; f < 4; ++f) {
            af[f]  = *reinterpret_cast<const bf16x8*>(&As[wr * 64 + f * 16 + (lane & 15)][koff]);
            bfr[f] = *reinterpret_cast<const bf16x8*>(&Bs[wc * 64 + f * 16 + (lane & 15)][koff]);
        }
        #pragma unroll
        for (int i = 0; i < 4; ++i)
            #pragma unroll
            for (int j = 0; j < 4; ++j)
                acc[i][j] = __builtin_amdgcn_mfma_f32_16x16x32_bf16(af[i], bfr[j], acc[i][j], 0, 0, 0);
        __syncthreads();
    }

    #pragma unroll
    for (int i = 0; i < 4; ++i) {
        #pragma unroll
        for (int q = 0; q < 4; ++q) {
            int gr = row0 + wr * 64 + i * 16 + (lane >> 4) * 4 + q;
            if (gr < n) {
                float dr = SCALE_OUT ? dinv[gr] : 1.0f;
                #pragma unroll
                for (int j = 0; j < 4; ++j) {
                    int gc = col0 + wc * 64 + j * 16 + (lane & 15);
                    C[(size_t)gr * M + gc] = f2bf(acc[i][j][q] * dr);
                }
            }
        }
    }

    if (STATS) {
        // per-column partial sums over this block's 128 rows (OOB rows contribute 0)
        #pragma unroll
        for (int j = 0; j < 4; ++j) {
            float s = 0.f, q = 0.f;
            #pragma unroll
            for (int i = 0; i < 4; ++i)
                #pragma unroll
                for (int p = 0; p < 4; ++p) {
                    float v = acc[i][j][p];
                    s += v; q += v * v;
                }
            s += __shfl_xor(s, 16, 64); s += __shfl_xor(s, 32, 64);
            q += __shfl_xor(q, 16, 64); q += __shfl_xor(q, 32, 64);
            if ((lane >> 4) == 0) {
                int gc = col0 + wc * 64 + j * 16 + (lane & 15);
                atomicAdd(&sums[gc], s);
                atomicAdd(&sqs[gc], q);
            }
        }
    }
}

// ---------------- batchnorm stats (vectorized) ----------------
template<int F>
__global__ __launch_bounds__(256) void bn_stats_k(const unsigned short* __restrict__ in,
                                                  float* __restrict__ stat, int n) {
    constexpr int G = F / 4;        // uint2 groups per row
    constexpr int RPB = 256 / G;    // rows per block-iteration
    int g  = threadIdx.x & (G - 1);
    int rl = threadIdx.x / G;
    float s[4] = {}, q[4] = {};
    for (int r = blockIdx.x * RPB + rl; r < n; r += gridDim.x * RPB) {
        uint2 u = *reinterpret_cast<const uint2*>(in + (size_t)r * F + g * 4);
        float v0 = bf2f((unsigned short)(u.x & 0xffff)), v1 = bf2f((unsigned short)(u.x >> 16));
        float v2 = bf2f((unsigned short)(u.y & 0xffff)), v3 = bf2f((unsigned short)(u.y >> 16));
        s[0] += v0; q[0] += v0 * v0;
        s[1] += v1; q[1] += v1 * v1;
        s[2] += v2; q[2] += v2 * v2;
        s[3] += v3; q[3] += v3 * v3;
    }
    #pragma unroll
    for (int k = 0; k < 4; ++k) {
        atomicAdd(&stat[g * 4 + k], s[k]);
        atomicAdd(&stat[F + g * 4 + k], q[k]);
    }
}

__global__ void bn_finalize_k(const float* __restrict__ stat,
                              const float* __restrict__ g, const float* __restrict__ be,
                              float* __restrict__ scale, float* __restrict__ shift,
                              int F, float invn) {
    int f = blockIdx.x * blockDim.x + threadIdx.x;
    if (f >= F) return;
    float mean = stat[f] * invn;
    float var  = stat[F + f] * invn - mean * mean;
    float rstd = rsqrtf(var + 1e-5f);
    float sc = g[f] * rstd;
    scale[f] = sc;
    shift[f] = be[f] - mean * sc;
}

// ---------------- pooling ----------------
__global__ void bounds_k(const int* __restrict__ batch, int* __restrict__ start, int n) {
    int i = blockIdx.x * blockDim.x + threadIdx.x;
    if (i >= n) return;
    int b = batch[i];
    if (i == 0) {
        for (int g = 0; g <= b; ++g) start[g] = 0;
    } else {
        int pb = batch[i - 1];
        for (int g = pb + 1; g <= b; ++g) start[g] = i;
    }
    if (i == n - 1) {
        for (int g = b + 1; g <= NGRAPHS; ++g) start[g] = n;
    }
}

__global__ __launch_bounds__(256) void pool_part_k(const unsigned short* __restrict__ a,
                                                   const int* __restrict__ start,
                                                   const float* __restrict__ scale,
                                                   const float* __restrict__ shift,
                                                   float* __restrict__ partial) {
    int g = blockIdx.x, q = blockIdx.y;
    int s = start[g], e = start[g + 1];
    int nr = e - s;
    int c0 = s + (nr * q) / 4, c1 = s + (nr * (q + 1)) / 4;
    int tf = threadIdx.x & 15, tr = threadIdx.x >> 4;

    float sc[8], sh[8];
    #pragma unroll
    for (int i = 0; i < 8; ++i) { sc[i] = scale[tf * 8 + i]; sh[i] = shift[tf * 8 + i]; }

    float acc[8] = {};
    for (int r = c0 + tr; r < c1; r += 16) {
        uint4 u = *reinterpret_cast<const uint4*>(a + (size_t)r * 128 + tf * 8);
        float v[8];
        v[0] = bf2f((unsigned short)(u.x & 0xffff)); v[1] = bf2f((unsigned short)(u.x >> 16));
        v[2] = bf2f((unsigned short)(u.y & 0xffff)); v[3] = bf2f((unsigned short)(u.y >> 16));
        v[4] = bf2f((unsigned short)(u.z & 0xffff)); v[5] = bf2f((unsigned short)(u.z >> 16));
        v[6] = bf2f((unsigned short)(u.w & 0xffff)); v[7] = bf2f((unsigned short)(u.w >> 16));
        #pragma unroll
        for (int i = 0; i < 8; ++i) acc[i] += fmaxf(v[i] * sc[i] + sh[i], 0.f);
    }

    __shared__ float red[16][128];
    #pragma unroll
    for (int i = 0; i < 8; ++i) red[tr][tf * 8 + i] = acc[i];
    __syncthreads();
    int f = threadIdx.x;
    if (f < 128) {
        float s2 = 0.f;
        #pragma unroll
        for (int t = 0; t < 16; ++t) s2 += red[t][f];
        partial[((size_t)(g * 4 + q)) * 128 + f] = s2;
    }
}

__global__ void final_out_k(const float* __restrict__ partial, const int* __restrict__ start,
                            const float* __restrict__ Wo, const float* __restrict__ bo,
                            float* __restrict__ out) {
    int idx = blockIdx.x * blockDim.x + threadIdx.x;
    if (idx >= NGRAPHS * 10) return;
    int g = idx / 10, c = idx - g * 10;
    float cntf = (float)(start[g + 1] - start[g]);
    float inv = 1.0f / fmaxf(cntf, 1.0f);
    float s = bo[c];
    for (int k = 0; k < 128; ++k) {
        float pk = partial[(size_t)(g * 4 + 0) * 128 + k] + partial[(size_t)(g * 4 + 1) * 128 + k]
                 + partial[(size_t)(g * 4 + 2) * 128 + k] + partial[(size_t)(g * 4 + 3) * 128 + k];
        s += pk * inv * Wo[k * 10 + c];
    }
    out[idx] = s;
}

// ---------------- driver ----------------
extern "C" void kernel_launch(void* const* d_in, const int* in_sizes, int n_in,
                              void* d_out, int out_size, void* d_ws, size_t ws_size,
                              hipStream_t stream) {
    const float* x   = (const float*)d_in[0];
    const int*   ei  = (const int*)d_in[1];
    const int*   bat = (const int*)d_in[2];
    const float* W1  = (const float*)d_in[3];
    const float* g1  = (const float*)d_in[5];
    const float* be1 = (const float*)d_in[6];
    const float* W2  = (const float*)d_in[7];
    const float* g2  = (const float*)d_in[9];
    const float* be2 = (const float*)d_in[10];
    const float* W3  = (const float*)d_in[11];
    const float* g3  = (const float*)d_in[13];
    const float* be3 = (const float*)d_in[14];
    const float* Wo  = (const float*)d_in[15];
    const float* bo  = (const float*)d_in[16];
    float* out = (float*)d_out;

    const int n  = in_sizes[2];       // 50000
    const int ne = in_sizes[1] / 2;   // 800000
    const int* row = ei;
    const int* col = ei + ne;
    const int NB = (n + 1023) / 1024; // scan blocks

    char* base = (char*)d_ws;
    size_t o = 0;
    auto alloc = [&](size_t bytes) -> char* {
        char* p = base + o;
        o += (bytes + 255) & ~(size_t)255;
        return p;
    };
    int*   cntfill = (int*)alloc((size_t)2 * n * 4);  // cnt | fill (one memset)
    int*   cnt  = cntfill;
    int*   fill = cntfill + n;
    int*   offs  = (int*)alloc(n * 4);
    int*   bsum  = (int*)alloc(256 * 4);
    float* dinv  = (float*)alloc(n * 4);
    int*   start = (int*)alloc((NGRAPHS + 1) * 4);
    float* stat  = (float*)alloc(1024 * 4);  // sums | sqs
    float* scale = (float*)alloc(512 * 4);
    float* shift = (float*)alloc(512 * 4);
    float* partial = (float*)alloc((size_t)NGRAPHS * 4 * 128 * 4);
    int*   csr_row = (int*)alloc((size_t)ne * 4);
    unsigned short* Wt1 = (unsigned short*)alloc((size_t)128 * 512 * 2);
    unsigned short* Wt2 = (unsigned short*)alloc((size_t)512 * 256 * 2);
    unsigned short* Wt3 = (unsigned short*)alloc((size_t)256 * 128 * 2);
    unsigned short* xs_bf  = (unsigned short*)alloc((size_t)n * 128 * 2);
    unsigned short* ax_bf  = (unsigned short*)alloc((size_t)n * 128 * 2);
    unsigned short* h1_bf  = (unsigned short*)alloc((size_t)n * 512 * 2);
    unsigned short* t2s_bf = (unsigned short*)alloc((size_t)n * 256 * 2);
    unsigned short* a2_bf  = (unsigned short*)alloc((size_t)n * 256 * 2);
    unsigned short* t3s_bf = (unsigned short*)alloc((size_t)n * 128 * 2);
    unsigned short* a3_bf  = (unsigned short*)alloc((size_t)n * 128 * 2);

    // ---- graph preprocessing ----
    hipMemsetAsync(cntfill, 0, (size_t)2 * n * sizeof(int), stream);
    deg_count_k<<<(ne + 255) / 256, 256, 0, stream>>>(col, cnt, ne);
    scan1_k<<<NB, 256, 0, stream>>>(cnt, offs, bsum, dinv, n);
    scan2_k<<<1, 256, 0, stream>>>(bsum, NB);
    scan3_k<<<NB, 256, 0, stream>>>(offs, bsum, n);
    scatter_k<<<(ne + 255) / 256, 256, 0, stream>>>(row, col, offs, fill, csr_row, ne);
    bounds_k<<<(n + 255) / 256, 256, 0, stream>>>(bat, start, n);

    // ---- conversions ----
    cvt_scale_k<<<(unsigned)(((long long)n * 32 + 255) / 256), 256, 0, stream>>>(x, dinv, xs_bf, n);
    wtrans_k<<<(128 * 512 + 255) / 256, 256, 0, stream>>>(W1, Wt1, 128, 512);
    wtrans_k<<<(512 * 256 + 255) / 256, 256, 0, stream>>>(W2, Wt2, 512, 256);
    wtrans_k<<<(256 * 128 + 255) / 256, 256, 0, stream>>>(W3, Wt3, 256, 128);

    // ---- Layer 1: agg(xs)[128] -> @W1 [512] (+fused column stats) ----
    agg_s_k<2><<<(n + 3) / 4, 256, 0, stream>>>(xs_bf, offs, cnt, csr_row, dinv, ax_bf, n);
    hipMemsetAsync(stat, 0, 1024 * sizeof(float), stream);
    gemm_bt_k<false, false, true><<<dim3(4, (n + 127) / 128), 256, 0, stream>>>(
        ax_bf, Wt1, h1_bf, nullptr, nullptr, nullptr, stat, stat + 512, n, 128, 512);
    bn_finalize_k<<<2, 256, 0, stream>>>(stat, g1, be1, scale, shift, 512, 1.0f / n);

    // ---- Layer 2: bn+relu(h1) @ W2 [256] (output prescaled) -> agg ----
    gemm_bt_k<true, true, false><<<dim3(2, (n + 127) / 128), 256, 0, stream>>>(
        h1_bf, Wt2, t2s_bf, scale, shift, dinv, nullptr, nullptr, n, 512, 256);
    agg_s_k<4><<<(n + 3) / 4, 256, 0, stream>>>(t2s_bf, offs, cnt, csr_row, dinv, a2_bf, n);
    hipMemsetAsync(stat, 0, 1024 * sizeof(float), stream);
    bn_stats_k<256><<<128, 256, 0, stream>>>(a2_bf, stat, n);
    bn_finalize_k<<<1, 256, 0, stream>>>(stat, g2, be2, scale, shift, 256, 1.0f / n);

    // ---- Layer 3: bn+relu(a2) @ W3 [128] (output prescaled) -> agg ----
    gemm_bt_k<true, true, false><<<dim3(1, (n + 127) / 128), 256, 0, stream>>>(
        a2_bf, Wt3, t3s_bf, scale, shift, dinv, nullptr, nullptr, n, 256, 128);
    agg_s_k<2><<<(n + 3) / 4, 256, 0, stream>>>(t3s_bf, offs, cnt, csr_row, dinv, a3_bf, n);
    hipMemsetAsync(stat, 0, 1024 * sizeof(float), stream);
    bn_stats_k<128><<<128, 256, 0, stream>>>(a3_bf, stat, n);
    bn_finalize_k<<<1, 256, 0, stream>>>(stat, g3, be3, scale, shift, 128, 1.0f / n);

    // ---- pool (fused BN+ReLU) + output ----
    pool_part_k<<<dim3(NGRAPHS, 4), 256, 0, stream>>>(a3_bf, start, scale, shift, partial);
    final_out_k<<<3, 256, 0, stream>>>(partial, start, Wo, bo, out);
}

// Round 7
// 527.443 us; speedup vs baseline: 12.2012x; 1.2434x over previous
//
#include <hip/hip_runtime.h>
#include <hip/hip_bf16.h>
#include <cstdint>
#include <cstddef>

#define NNODES 50000
#define NGRAPHS 64

typedef short bf16x8 __attribute__((ext_vector_type(8)));
typedef float f32x4 __attribute__((ext_vector_type(4)));

__device__ inline float bf2f(unsigned short u) {
    return __uint_as_float(((unsigned)u) << 16);
}
__device__ inline unsigned short f2bf(float f) {
    unsigned u = __float_as_uint(f);
    return (unsigned short)((u + 0x7fff + ((u >> 16) & 1)) >> 16);  // RNE
}

// ---------------- degree ----------------
__global__ void deg_count_k(const int* __restrict__ col, int* __restrict__ cnt, int ne) {
    int i = blockIdx.x * blockDim.x + threadIdx.x;
    if (i < ne) atomicAdd(&cnt[col[i]], 1);
}

// ---------------- multi-block exclusive scan (1024 elems/block) + dinv ----------------
__global__ __launch_bounds__(256) void scan1_k(const int* __restrict__ cnt, int* __restrict__ offs,
                                               int* __restrict__ bsum, float* __restrict__ dinv, int n) {
    int t = threadIdx.x;
    int base = blockIdx.x * 1024 + t * 4;
    int4 v = {0, 0, 0, 0};
    if (base + 3 < n) v = *reinterpret_cast<const int4*>(cnt + base);
    else {
        if (base + 0 < n) v.x = cnt[base + 0];
        if (base + 1 < n) v.y = cnt[base + 1];
        if (base + 2 < n) v.z = cnt[base + 2];
    }
    if (base + 0 < n) dinv[base + 0] = rsqrtf((float)(v.x + 1));
    if (base + 1 < n) dinv[base + 1] = rsqrtf((float)(v.y + 1));
    if (base + 2 < n) dinv[base + 2] = rsqrtf((float)(v.z + 1));
    if (base + 3 < n) dinv[base + 3] = rsqrtf((float)(v.w + 1));

    int s = v.x + v.y + v.z + v.w;
    __shared__ int lds[256];
    lds[t] = s;
    __syncthreads();
    #pragma unroll
    for (int d = 1; d < 256; d <<= 1) {
        int u = (t >= d) ? lds[t - d] : 0;
        __syncthreads();
        lds[t] += u;
        __syncthreads();
    }
    int excl = lds[t] - s;
    if (t == 255) bsum[blockIdx.x] = lds[t];

    if (base + 3 < n) {
        int4 o;
        o.x = excl; o.y = excl + v.x; o.z = o.y + v.y; o.w = o.z + v.z;
        *reinterpret_cast<int4*>(offs + base) = o;
    } else {
        int e = excl;
        if (base + 0 < n) { offs[base + 0] = e; e += v.x; }
        if (base + 1 < n) { offs[base + 1] = e; e += v.y; }
        if (base + 2 < n) { offs[base + 2] = e; }
    }
}

__global__ __launch_bounds__(256) void scan2_k(int* __restrict__ bsum, int nb) {
    __shared__ int lds[256];
    int t = threadIdx.x;
    int v = (t < nb) ? bsum[t] : 0;
    lds[t] = v;
    __syncthreads();
    #pragma unroll
    for (int d = 1; d < 256; d <<= 1) {
        int u = (t >= d) ? lds[t - d] : 0;
        __syncthreads();
        lds[t] += u;
        __syncthreads();
    }
    if (t < nb) bsum[t] = lds[t] - v;  // exclusive
}

__global__ __launch_bounds__(256) void scan3_k(int* __restrict__ offs, const int* __restrict__ bsum, int n) {
    int base = blockIdx.x * 1024 + threadIdx.x * 4;
    int add = bsum[blockIdx.x];
    if (base + 3 < n) {
        int4 o = *reinterpret_cast<int4*>(offs + base);
        o.x += add; o.y += add; o.z += add; o.w += add;
        *reinterpret_cast<int4*>(offs + base) = o;
    } else {
        for (int k = 0; k < 4; ++k)
            if (base + k < n) offs[base + k] += add;
    }
}

// ---------------- CSR scatter ----------------
__global__ void scatter_k(const int* __restrict__ row_, const int* __restrict__ col_,
                          const int* __restrict__ offs, int* __restrict__ fill,
                          int* __restrict__ csr_row, int ne) {
    int e = blockIdx.x * blockDim.x + threadIdx.x;
    if (e >= ne) return;
    int r = row_[e], c = col_[e];
    int pos = offs[c] + atomicAdd(&fill[c], 1);
    csr_row[pos] = r;
}

// ---------------- fp32 -> bf16 with per-row dinv prescale ----------------
__global__ void cvt_scale_k(const float* __restrict__ in, const float* __restrict__ dinv,
                            unsigned short* __restrict__ out, int n) {
    long long i = (long long)blockIdx.x * blockDim.x + threadIdx.x;
    long long total4 = (long long)n * 32;
    if (i >= total4) return;
    int r = (int)(i >> 5);
    float d = dinv[r];
    float4 v = reinterpret_cast<const float4*>(in)[i];
    uint2 o;
    o.x = (unsigned)f2bf(v.x * d) | ((unsigned)f2bf(v.y * d) << 16);
    o.y = (unsigned)f2bf(v.z * d) | ((unsigned)f2bf(v.w * d) << 16);
    reinterpret_cast<uint2*>(out)[i] = o;
}

// ---------------- weight transpose + convert ----------------
__global__ void wtrans_k(const float* __restrict__ W, unsigned short* __restrict__ Wt, int K, int M) {
    int idx = blockIdx.x * blockDim.x + threadIdx.x;
    if (idx >= K * M) return;
    int k = idx / M, m = idx - k * M;
    Wt[(size_t)m * K + k] = f2bf(W[idx]);
}

// ---------------- row load helper ----------------
template<int FC>
__device__ inline void loadrow(const unsigned short* __restrict__ p, float* v) {
    if constexpr (FC == 2) {
        unsigned u = *reinterpret_cast<const unsigned*>(p);
        v[0] = bf2f((unsigned short)(u & 0xffff));
        v[1] = bf2f((unsigned short)(u >> 16));
    } else {
        uint2 u = *reinterpret_cast<const uint2*>(p);
        v[0] = bf2f((unsigned short)(u.x & 0xffff));
        v[1] = bf2f((unsigned short)(u.x >> 16));
        v[2] = bf2f((unsigned short)(u.y & 0xffff));
        v[3] = bf2f((unsigned short)(u.y >> 16));
    }
}

// ---------------- CSR aggregation: one wave per node, prescaled input ----------------
template<int FC>
__global__ void agg_s_k(const unsigned short* __restrict__ in, const int* __restrict__ offs,
                        const int* __restrict__ cnt, const int* __restrict__ csr_row,
                        const float* __restrict__ dinv, unsigned short* __restrict__ out, int n) {
    const int F = 64 * FC;
    int node = blockIdx.x * (blockDim.x >> 6) + (threadIdx.x >> 6);
    if (node >= n) return;
    int lane = threadIdx.x & 63;
    const size_t foff = (size_t)lane * FC;

    float acc[FC];
    loadrow<FC>(in + (size_t)node * F + foff, acc);  // self term

    int s = offs[node], e1 = s + cnt[node];
    int e = s;
    for (; e + 4 <= e1; e += 4) {
        int r0 = csr_row[e], r1 = csr_row[e + 1], r2 = csr_row[e + 2], r3 = csr_row[e + 3];
        float v0[FC], v1[FC], v2[FC], v3[FC];
        loadrow<FC>(in + (size_t)r0 * F + foff, v0);
        loadrow<FC>(in + (size_t)r1 * F + foff, v1);
        loadrow<FC>(in + (size_t)r2 * F + foff, v2);
        loadrow<FC>(in + (size_t)r3 * F + foff, v3);
        #pragma unroll
        for (int i = 0; i < FC; ++i) acc[i] += (v0[i] + v1[i]) + (v2[i] + v3[i]);
    }
    for (; e < e1; ++e) {
        int r0 = csr_row[e];
        float v0[FC];
        loadrow<FC>(in + (size_t)r0 * F + foff, v0);
        #pragma unroll
        for (int i = 0; i < FC; ++i) acc[i] += v0[i];
    }

    float d = dinv[node];
    unsigned short* q = out + (size_t)node * F + foff;
    if constexpr (FC == 2) {
        unsigned o = (unsigned)f2bf(acc[0] * d) | ((unsigned)f2bf(acc[1] * d) << 16);
        *reinterpret_cast<unsigned*>(q) = o;
    } else {
        uint2 o;
        o.x = (unsigned)f2bf(acc[0] * d) | ((unsigned)f2bf(acc[1] * d) << 16);
        o.y = (unsigned)f2bf(acc[2] * d) | ((unsigned)f2bf(acc[3] * d) << 16);
        *reinterpret_cast<uint2*>(q) = o;
    }
}

// ---------------- bf16 MFMA GEMM ----------------
template<bool BN_A, bool SCALE_OUT, bool STATS>
__global__ __launch_bounds__(256) void gemm_bt_k(const unsigned short* __restrict__ A,
                                                 const unsigned short* __restrict__ B,
                                                 unsigned short* __restrict__ C,
                                                 const float* __restrict__ scale,
                                                 const float* __restrict__ shift,
                                                 const float* __restrict__ dinv,
                                                 float* __restrict__ sums,
                                                 float* __restrict__ sqs,
                                                 int n, int K, int M) {
    __shared__ unsigned short As[128][40];
    __shared__ unsigned short Bs[128][40];
    int tid = threadIdx.x;
    int wid = tid >> 6, lane = tid & 63;
    int wr = wid >> 1, wc = wid & 1;
    int row0 = blockIdx.y * 128, col0 = blockIdx.x * 128;

    f32x4 acc[4][4] = {};

    for (int kt = 0; kt < K; kt += 32) {
        int c8 = (tid & 3) * 8;
        float4 sc0, sc1, sh0, sh1;
        if (BN_A) {
            sc0 = *reinterpret_cast<const float4*>(scale + kt + c8);
            sc1 = *reinterpret_cast<const float4*>(scale + kt + c8 + 4);
            sh0 = *reinterpret_cast<const float4*>(shift + kt + c8);
            sh1 = *reinterpret_cast<const float4*>(shift + kt + c8 + 4);
        }
        #pragma unroll
        for (int h = 0; h < 2; ++h) {
            int r = (tid >> 2) + h * 64;
            int gr = row0 + r;
            bf16x8 va = {};
            if (gr < n) va = *reinterpret_cast<const bf16x8*>(A + (size_t)gr * K + kt + c8);
            if (BN_A) {
                #pragma unroll
                for (int t = 0; t < 8; ++t) {
                    float sct = (t < 4) ? (&sc0.x)[t] : (&sc1.x)[t - 4];
                    float sht = (t < 4) ? (&sh0.x)[t] : (&sh1.x)[t - 4];
                    float f = bf2f((unsigned short)va[t]);
                    va[t] = (short)f2bf(fmaxf(f * sct + sht, 0.f));
                }
            }
            *reinterpret_cast<bf16x8*>(&As[r][c8]) = va;
            bf16x8 vb = *reinterpret_cast<const bf16x8*>(B + (size_t)(col0 + r) * K + kt + c8);
            *reinterpret_cast<bf16x8*>(&Bs[r][c8]) = vb;
        }
        __syncthreads();

        bf16x8 af[4], bfr[4];
        int koff = (lane >> 4) * 8;
        #pragma unroll
        for (int f = 0; f < 4; ++f) {
            af[f]  = *reinterpret_cast<const bf16x8*>(&As[wr * 64 + f * 16 + (lane & 15)][koff]);
            bfr[f] = *reinterpret_cast<const bf16x8*>(&Bs[wc * 64 + f * 16 + (lane & 15)][koff]);
        }
        #pragma unroll
        for (int i = 0; i < 4; ++i)
            #pragma unroll
            for (int j = 0; j < 4; ++j)
                acc[i][j] = __builtin_amdgcn_mfma_f32_16x16x32_bf16(af[i], bfr[j], acc[i][j], 0, 0, 0);
        __syncthreads();
    }

    #pragma unroll
    for (int i = 0; i < 4; ++i) {
        #pragma unroll
        for (int q = 0; q < 4; ++q) {
            int gr = row0 + wr * 64 + i * 16 + (lane >> 4) * 4 + q;
            if (gr < n) {
                float dr = SCALE_OUT ? dinv[gr] : 1.0f;
                #pragma unroll
                for (int j = 0; j < 4; ++j) {
                    int gc = col0 + wc * 64 + j * 16 + (lane & 15);
                    C[(size_t)gr * M + gc] = f2bf(acc[i][j][q] * dr);
                }
            }
        }
    }

    if (STATS) {
        #pragma unroll
        for (int j = 0; j < 4; ++j) {
            float s = 0.f, q = 0.f;
            #pragma unroll
            for (int i = 0; i < 4; ++i)
                #pragma unroll
                for (int p = 0; p < 4; ++p) {
                    float v = acc[i][j][p];
                    s += v; q += v * v;
                }
            s += __shfl_xor(s, 16, 64); s += __shfl_xor(s, 32, 64);
            q += __shfl_xor(q, 16, 64); q += __shfl_xor(q, 32, 64);
            if ((lane >> 4) == 0) {
                int gc = col0 + wc * 64 + j * 16 + (lane & 15);
                atomicAdd(&sums[gc], s);
                atomicAdd(&sqs[gc], q);
            }
        }
    }
}

// ---------------- batchnorm stats: uint4 loads, LDS block-reduce, 2F atomics/block ----------------
template<int F>
__global__ __launch_bounds__(256) void bn_stats_k(const unsigned short* __restrict__ in,
                                                  float* __restrict__ stat, int n) {
    constexpr int G   = F / 8;    // threads covering one row (8 bf16 each)
    constexpr int RPP = 256 / G;  // rows per pass
    int g  = threadIdx.x & (G - 1);
    int rl = threadIdx.x / G;

    float s[8] = {}, q[8] = {};
    for (int r = blockIdx.x * RPP + rl; r < n; r += gridDim.x * RPP) {
        uint4 u = *reinterpret_cast<const uint4*>(in + (size_t)r * F + g * 8);
        float v[8];
        v[0] = bf2f((unsigned short)(u.x & 0xffff)); v[1] = bf2f((unsigned short)(u.x >> 16));
        v[2] = bf2f((unsigned short)(u.y & 0xffff)); v[3] = bf2f((unsigned short)(u.y >> 16));
        v[4] = bf2f((unsigned short)(u.z & 0xffff)); v[5] = bf2f((unsigned short)(u.z >> 16));
        v[6] = bf2f((unsigned short)(u.w & 0xffff)); v[7] = bf2f((unsigned short)(u.w >> 16));
        #pragma unroll
        for (int i = 0; i < 8; ++i) { s[i] += v[i]; q[i] += v[i] * v[i]; }
    }

    __shared__ float lds[RPP][F];
    #pragma unroll
    for (int i = 0; i < 8; ++i) lds[rl][g * 8 + i] = s[i];
    __syncthreads();
    if (threadIdx.x < F) {
        float t = 0.f;
        #pragma unroll
        for (int rr = 0; rr < RPP; ++rr) t += lds[rr][threadIdx.x];
        atomicAdd(&stat[threadIdx.x], t);
    }
    __syncthreads();
    #pragma unroll
    for (int i = 0; i < 8; ++i) lds[rl][g * 8 + i] = q[i];
    __syncthreads();
    if (threadIdx.x < F) {
        float t = 0.f;
        #pragma unroll
        for (int rr = 0; rr < RPP; ++rr) t += lds[rr][threadIdx.x];
        atomicAdd(&stat[F + threadIdx.x], t);
    }
}

__global__ void bn_finalize_k(const float* __restrict__ stat,
                              const float* __restrict__ g, const float* __restrict__ be,
                              float* __restrict__ scale, float* __restrict__ shift,
                              int F, float invn) {
    int f = blockIdx.x * blockDim.x + threadIdx.x;
    if (f >= F) return;
    float mean = stat[f] * invn;
    float var  = stat[F + f] * invn - mean * mean;
    float rstd = rsqrtf(var + 1e-5f);
    float sc = g[f] * rstd;
    scale[f] = sc;
    shift[f] = be[f] - mean * sc;
}

// ---------------- pooling ----------------
__global__ void bounds_k(const int* __restrict__ batch, int* __restrict__ start, int n) {
    int i = blockIdx.x * blockDim.x + threadIdx.x;
    if (i >= n) return;
    int b = batch[i];
    if (i == 0) {
        for (int g = 0; g <= b; ++g) start[g] = 0;
    } else {
        int pb = batch[i - 1];
        for (int g = pb + 1; g <= b; ++g) start[g] = i;
    }
    if (i == n - 1) {
        for (int g = b + 1; g <= NGRAPHS; ++g) start[g] = n;
    }
}

__global__ __launch_bounds__(256) void pool_part_k(const unsigned short* __restrict__ a,
                                                   const int* __restrict__ start,
                                                   const float* __restrict__ scale,
                                                   const float* __restrict__ shift,
                                                   float* __restrict__ partial) {
    int g = blockIdx.x, q = blockIdx.y;
    int s = start[g], e = start[g + 1];
    int nr = e - s;
    int c0 = s + (nr * q) / 4, c1 = s + (nr * (q + 1)) / 4;
    int tf = threadIdx.x & 15, tr = threadIdx.x >> 4;

    float sc[8], sh[8];
    #pragma unroll
    for (int i = 0; i < 8; ++i) { sc[i] = scale[tf * 8 + i]; sh[i] = shift[tf * 8 + i]; }

    float acc[8] = {};
    for (int r = c0 + tr; r < c1; r += 16) {
        uint4 u = *reinterpret_cast<const uint4*>(a + (size_t)r * 128 + tf * 8);
        float v[8];
        v[0] = bf2f((unsigned short)(u.x & 0xffff)); v[1] = bf2f((unsigned short)(u.x >> 16));
        v[2] = bf2f((unsigned short)(u.y & 0xffff)); v[3] = bf2f((unsigned short)(u.y >> 16));
        v[4] = bf2f((unsigned short)(u.z & 0xffff)); v[5] = bf2f((unsigned short)(u.z >> 16));
        v[6] = bf2f((unsigned short)(u.w & 0xffff)); v[7] = bf2f((unsigned short)(u.w >> 16));
        #pragma unroll
        for (int i = 0; i < 8; ++i) acc[i] += fmaxf(v[i] * sc[i] + sh[i], 0.f);
    }

    __shared__ float red[16][128];
    #pragma unroll
    for (int i = 0; i < 8; ++i) red[tr][tf * 8 + i] = acc[i];
    __syncthreads();
    int f = threadIdx.x;
    if (f < 128) {
        float s2 = 0.f;
        #pragma unroll
        for (int t = 0; t < 16; ++t) s2 += red[t][f];
        partial[((size_t)(g * 4 + q)) * 128 + f] = s2;
    }
}

__global__ void final_out_k(const float* __restrict__ partial, const int* __restrict__ start,
                            const float* __restrict__ Wo, const float* __restrict__ bo,
                            float* __restrict__ out) {
    int idx = blockIdx.x * blockDim.x + threadIdx.x;
    if (idx >= NGRAPHS * 10) return;
    int g = idx / 10, c = idx - g * 10;
    float cntf = (float)(start[g + 1] - start[g]);
    float inv = 1.0f / fmaxf(cntf, 1.0f);
    float s = bo[c];
    for (int k = 0; k < 128; ++k) {
        float pk = partial[(size_t)(g * 4 + 0) * 128 + k] + partial[(size_t)(g * 4 + 1) * 128 + k]
                 + partial[(size_t)(g * 4 + 2) * 128 + k] + partial[(size_t)(g * 4 + 3) * 128 + k];
        s += pk * inv * Wo[k * 10 + c];
    }
    out[idx] = s;
}

// ---------------- driver ----------------
extern "C" void kernel_launch(void* const* d_in, const int* in_sizes, int n_in,
                              void* d_out, int out_size, void* d_ws, size_t ws_size,
                              hipStream_t stream) {
    const float* x   = (const float*)d_in[0];
    const int*   ei  = (const int*)d_in[1];
    const int*   bat = (const int*)d_in[2];
    const float* W1  = (const float*)d_in[3];
    const float* g1  = (const float*)d_in[5];
    const float* be1 = (const float*)d_in[6];
    const float* W2  = (const float*)d_in[7];
    const float* g2  = (const float*)d_in[9];
    const float* be2 = (const float*)d_in[10];
    const float* W3  = (const float*)d_in[11];
    const float* g3  = (const float*)d_in[13];
    const float* be3 = (const float*)d_in[14];
    const float* Wo  = (const float*)d_in[15];
    const float* bo  = (const float*)d_in[16];
    float* out = (float*)d_out;

    const int n  = in_sizes[2];       // 50000
    const int ne = in_sizes[1] / 2;   // 800000
    const int* row = ei;
    const int* col = ei + ne;
    const int NB = (n + 1023) / 1024; // scan blocks

    char* base = (char*)d_ws;
    size_t o = 0;
    auto alloc = [&](size_t bytes) -> char* {
        char* p = base + o;
        o += (bytes + 255) & ~(size_t)255;
        return p;
    };
    int*   cntfill = (int*)alloc((size_t)2 * n * 4);  // cnt | fill (one memset)
    int*   cnt  = cntfill;
    int*   fill = cntfill + n;
    int*   offs  = (int*)alloc(n * 4);
    int*   bsum  = (int*)alloc(256 * 4);
    float* dinv  = (float*)alloc(n * 4);
    int*   start = (int*)alloc((NGRAPHS + 1) * 4);
    float* stat  = (float*)alloc(1024 * 4);  // sums | sqs
    float* scale = (float*)alloc(512 * 4);
    float* shift = (float*)alloc(512 * 4);
    float* partial = (float*)alloc((size_t)NGRAPHS * 4 * 128 * 4);
    int*   csr_row = (int*)alloc((size_t)ne * 4);
    unsigned short* Wt1 = (unsigned short*)alloc((size_t)128 * 512 * 2);
    unsigned short* Wt2 = (unsigned short*)alloc((size_t)512 * 256 * 2);
    unsigned short* Wt3 = (unsigned short*)alloc((size_t)256 * 128 * 2);
    unsigned short* xs_bf  = (unsigned short*)alloc((size_t)n * 128 * 2);
    unsigned short* ax_bf  = (unsigned short*)alloc((size_t)n * 128 * 2);
    unsigned short* h1_bf  = (unsigned short*)alloc((size_t)n * 512 * 2);
    unsigned short* t2s_bf = (unsigned short*)alloc((size_t)n * 256 * 2);
    unsigned short* a2_bf  = (unsigned short*)alloc((size_t)n * 256 * 2);
    unsigned short* t3s_bf = (unsigned short*)alloc((size_t)n * 128 * 2);
    unsigned short* a3_bf  = (unsigned short*)alloc((size_t)n * 128 * 2);

    // ---- graph preprocessing ----
    hipMemsetAsync(cntfill, 0, (size_t)2 * n * sizeof(int), stream);
    deg_count_k<<<(ne + 255) / 256, 256, 0, stream>>>(col, cnt, ne);
    scan1_k<<<NB, 256, 0, stream>>>(cnt, offs, bsum, dinv, n);
    scan2_k<<<1, 256, 0, stream>>>(bsum, NB);
    scan3_k<<<NB, 256, 0, stream>>>(offs, bsum, n);
    scatter_k<<<(ne + 255) / 256, 256, 0, stream>>>(row, col, offs, fill, csr_row, ne);
    bounds_k<<<(n + 255) / 256, 256, 0, stream>>>(bat, start, n);

    // ---- conversions ----
    cvt_scale_k<<<(unsigned)(((long long)n * 32 + 255) / 256), 256, 0, stream>>>(x, dinv, xs_bf, n);
    wtrans_k<<<(128 * 512 + 255) / 256, 256, 0, stream>>>(W1, Wt1, 128, 512);
    wtrans_k<<<(512 * 256 + 255) / 256, 256, 0, stream>>>(W2, Wt2, 512, 256);
    wtrans_k<<<(256 * 128 + 255) / 256, 256, 0, stream>>>(W3, Wt3, 256, 128);

    // ---- Layer 1: agg(xs)[128] -> @W1 [512] (+fused column stats) ----
    agg_s_k<2><<<(n + 3) / 4, 256, 0, stream>>>(xs_bf, offs, cnt, csr_row, dinv, ax_bf, n);
    hipMemsetAsync(stat, 0, 1024 * sizeof(float), stream);
    gemm_bt_k<false, false, true><<<dim3(4, (n + 127) / 128), 256, 0, stream>>>(
        ax_bf, Wt1, h1_bf, nullptr, nullptr, nullptr, stat, stat + 512, n, 128, 512);
    bn_finalize_k<<<2, 256, 0, stream>>>(stat, g1, be1, scale, shift, 512, 1.0f / n);

    // ---- Layer 2: bn+relu(h1) @ W2 [256] (output prescaled) -> agg ----
    gemm_bt_k<true, true, false><<<dim3(2, (n + 127) / 128), 256, 0, stream>>>(
        h1_bf, Wt2, t2s_bf, scale, shift, dinv, nullptr, nullptr, n, 512, 256);
    agg_s_k<4><<<(n + 3) / 4, 256, 0, stream>>>(t2s_bf, offs, cnt, csr_row, dinv, a2_bf, n);
    hipMemsetAsync(stat, 0, 1024 * sizeof(float), stream);
    bn_stats_k<256><<<1024, 256, 0, stream>>>(a2_bf, stat, n);
    bn_finalize_k<<<1, 256, 0, stream>>>(stat, g2, be2, scale, shift, 256, 1.0f / n);

    // ---- Layer 3: bn+relu(a2) @ W3 [128] (output prescaled) -> agg ----
    gemm_bt_k<true, true, false><<<dim3(1, (n + 127) / 128), 256, 0, stream>>>(
        a2_bf, Wt3, t3s_bf, scale, shift, dinv, nullptr, nullptr, n, 256, 128);
    agg_s_k<2><<<(n + 3) / 4, 256, 0, stream>>>(t3s_bf, offs, cnt, csr_row, dinv, a3_bf, n);
    hipMemsetAsync(stat, 0, 1024 * sizeof(float), stream);
    bn_stats_k<128><<<1024, 256, 0, stream>>>(a3_bf, stat, n);
    bn_finalize_k<<<1, 256, 0, stream>>>(stat, g3, be3, scale, shift, 128, 1.0f / n);

    // ---- pool (fused BN+ReLU) + output ----
    pool_part_k<<<dim3(NGRAPHS, 4), 256, 0, stream>>>(a3_bf, start, scale, shift, partial);
    final_out_k<<<3, 256, 0, stream>>>(partial, start, Wo, bo, out);
}

// Round 9
// 506.185 us; speedup vs baseline: 12.7136x; 1.0420x over previous
//
#include <hip/hip_runtime.h>
#include <hip/hip_bf16.h>
#include <cstdint>
#include <cstddef>

#define NNODES 50000
#define NGRAPHS 64

typedef short bf16x8 __attribute__((ext_vector_type(8)));
typedef float f32x4 __attribute__((ext_vector_type(4)));

__device__ inline float bf2f(unsigned short u) {
    return __uint_as_float(((unsigned)u) << 16);
}
__device__ inline unsigned short f2bf(float f) {
    unsigned u = __float_as_uint(f);
    return (unsigned short)((u + 0x7fff + ((u >> 16) & 1)) >> 16);  // RNE
}
__device__ inline void unpack8(uint4 u, float* v) {
    v[0] = bf2f((unsigned short)(u.x & 0xffff)); v[1] = bf2f((unsigned short)(u.x >> 16));
    v[2] = bf2f((unsigned short)(u.y & 0xffff)); v[3] = bf2f((unsigned short)(u.y >> 16));
    v[4] = bf2f((unsigned short)(u.z & 0xffff)); v[5] = bf2f((unsigned short)(u.z >> 16));
    v[6] = bf2f((unsigned short)(u.w & 0xffff)); v[7] = bf2f((unsigned short)(u.w >> 16));
}

// ---------------- degree ----------------
__global__ void deg_count_k(const int* __restrict__ col, int* __restrict__ cnt, int ne) {
    int i = blockIdx.x * blockDim.x + threadIdx.x;
    if (i < ne) atomicAdd(&cnt[col[i]], 1);
}

// ---------------- multi-block exclusive scan (1024 elems/block) + dinv ----------------
__global__ __launch_bounds__(256) void scan1_k(const int* __restrict__ cnt, int* __restrict__ offs,
                                               int* __restrict__ bsum, float* __restrict__ dinv, int n) {
    int t = threadIdx.x;
    int base = blockIdx.x * 1024 + t * 4;
    int4 v = {0, 0, 0, 0};
    if (base + 3 < n) v = *reinterpret_cast<const int4*>(cnt + base);
    else {
        if (base + 0 < n) v.x = cnt[base + 0];
        if (base + 1 < n) v.y = cnt[base + 1];
        if (base + 2 < n) v.z = cnt[base + 2];
    }
    if (base + 0 < n) dinv[base + 0] = rsqrtf((float)(v.x + 1));
    if (base + 1 < n) dinv[base + 1] = rsqrtf((float)(v.y + 1));
    if (base + 2 < n) dinv[base + 2] = rsqrtf((float)(v.z + 1));
    if (base + 3 < n) dinv[base + 3] = rsqrtf((float)(v.w + 1));

    int s = v.x + v.y + v.z + v.w;
    __shared__ int lds[256];
    lds[t] = s;
    __syncthreads();
    #pragma unroll
    for (int d = 1; d < 256; d <<= 1) {
        int u = (t >= d) ? lds[t - d] : 0;
        __syncthreads();
        lds[t] += u;
        __syncthreads();
    }
    int excl = lds[t] - s;
    if (t == 255) bsum[blockIdx.x] = lds[t];

    if (base + 3 < n) {
        int4 o;
        o.x = excl; o.y = excl + v.x; o.z = o.y + v.y; o.w = o.z + v.z;
        *reinterpret_cast<int4*>(offs + base) = o;
    } else {
        int e = excl;
        if (base + 0 < n) { offs[base + 0] = e; e += v.x; }
        if (base + 1 < n) { offs[base + 1] = e; e += v.y; }
        if (base + 2 < n) { offs[base + 2] = e; }
    }
}

__global__ __launch_bounds__(256) void scan2_k(int* __restrict__ bsum, int nb) {
    __shared__ int lds[256];
    int t = threadIdx.x;
    int v = (t < nb) ? bsum[t] : 0;
    lds[t] = v;
    __syncthreads();
    #pragma unroll
    for (int d = 1; d < 256; d <<= 1) {
        int u = (t >= d) ? lds[t - d] : 0;
        __syncthreads();
        lds[t] += u;
        __syncthreads();
    }
    if (t < nb) bsum[t] = lds[t] - v;  // exclusive
}

__global__ __launch_bounds__(256) void scan3_k(int* __restrict__ offs, const int* __restrict__ bsum, int n) {
    int base = blockIdx.x * 1024 + threadIdx.x * 4;
    int add = bsum[blockIdx.x];
    if (base + 3 < n) {
        int4 o = *reinterpret_cast<int4*>(offs + base);
        o.x += add; o.y += add; o.z += add; o.w += add;
        *reinterpret_cast<int4*>(offs + base) = o;
    } else {
        for (int k = 0; k < 4; ++k)
            if (base + k < n) offs[base + k] += add;
    }
}

// ---------------- CSR scatter ----------------
__global__ void scatter_k(const int* __restrict__ row_, const int* __restrict__ col_,
                          const int* __restrict__ offs, int* __restrict__ fill,
                          int* __restrict__ csr_row, int ne) {
    int e = blockIdx.x * blockDim.x + threadIdx.x;
    if (e >= ne) return;
    int r = row_[e], c = col_[e];
    int pos = offs[c] + atomicAdd(&fill[c], 1);
    csr_row[pos] = r;
}

// ---------------- fp32 -> bf16 with per-row dinv prescale ----------------
__global__ void cvt_scale_k(const float* __restrict__ in, const float* __restrict__ dinv,
                            unsigned short* __restrict__ out, int n) {
    long long i = (long long)blockIdx.x * blockDim.x + threadIdx.x;
    long long total4 = (long long)n * 32;
    if (i >= total4) return;
    int r = (int)(i >> 5);
    float d = dinv[r];
    float4 v = reinterpret_cast<const float4*>(in)[i];
    uint2 o;
    o.x = (unsigned)f2bf(v.x * d) | ((unsigned)f2bf(v.y * d) << 16);
    o.y = (unsigned)f2bf(v.z * d) | ((unsigned)f2bf(v.w * d) << 16);
    reinterpret_cast<uint2*>(out)[i] = o;
}

// ---------------- all weights transpose + convert (one launch) ----------------
__global__ void wtrans_all_k(const float* __restrict__ W1, const float* __restrict__ W2,
                             const float* __restrict__ W3,
                             unsigned short* __restrict__ Wt1, unsigned short* __restrict__ Wt2,
                             unsigned short* __restrict__ Wt3) {
    int idx = blockIdx.x * blockDim.x + threadIdx.x;
    if (idx < 65536) {                      // W1: 128x512
        int k = idx >> 9, m = idx & 511;
        Wt1[m * 128 + k] = f2bf(W1[idx]);
    } else if (idx < 196608) {              // W2: 512x256
        int j = idx - 65536;
        int k = j >> 8, m = j & 255;
        Wt2[m * 512 + k] = f2bf(W2[j]);
    } else if (idx < 229376) {              // W3: 256x128
        int j = idx - 196608;
        int k = j >> 7, m = j & 127;
        Wt3[m * 256 + k] = f2bf(W3[j]);
    }
}

// ---------------- CSR aggregation: multi-edge waves, uint4 (16B) lanes ----------------
// FC: F = 64*FC. F=256: 32 lanes/row, 2 edges/iter. F=128: 16 lanes/row, 4 edges/iter.
// out[c] = f2bf( dinv[c] * ( in[c] + sum_{e in CSR[c]} in[row[e]] ) )   (input prescaled by dinv[r])
template<int FC>
__global__ void agg_s_k(const unsigned short* __restrict__ in, const int* __restrict__ offs,
                        const int* __restrict__ cnt, const int* __restrict__ csr_row,
                        const float* __restrict__ dinv, unsigned short* __restrict__ out, int n) {
    constexpr int F   = 64 * FC;
    constexpr int LPE = (FC == 4) ? 32 : 16;   // lanes covering one row
    constexpr int EPL = 64 / LPE;              // edges per wave-iteration
    int node = blockIdx.x * 4 + (threadIdx.x >> 6);
    if (node >= n) return;
    int lane = threadIdx.x & 63;
    int sub = lane / LPE;          // which edge slot
    int fl  = lane % LPE;          // feature-lane within row
    const size_t foff = (size_t)fl * 8;

    float acc[8] = {};
    if (sub == 0) {  // self term, counted once
        uint4 u = *reinterpret_cast<const uint4*>(in + (size_t)node * F + foff);
        float v[8]; unpack8(u, v);
        #pragma unroll
        for (int i = 0; i < 8; ++i) acc[i] = v[i];
    }

    int s = offs[node], e1 = s + cnt[node];
    int eb = s;
    // main: 2*EPL edges per iteration, no predication
    for (; eb + 2 * EPL <= e1; eb += 2 * EPL) {
        int r0 = csr_row[eb + sub];
        int r1 = csr_row[eb + EPL + sub];
        uint4 u0 = *reinterpret_cast<const uint4*>(in + (size_t)r0 * F + foff);
        uint4 u1 = *reinterpret_cast<const uint4*>(in + (size_t)r1 * F + foff);
        float v0[8], v1[8];
        unpack8(u0, v0); unpack8(u1, v1);
        #pragma unroll
        for (int i = 0; i < 8; ++i) acc[i] += v0[i] + v1[i];
    }
    // tail: predicated
    for (; eb < e1; eb += EPL) {
        int e = eb + sub;
        bool ok = e < e1;
        int r = csr_row[ok ? e : e1 - 1];
        uint4 u = *reinterpret_cast<const uint4*>(in + (size_t)r * F + foff);
        float v[8]; unpack8(u, v);
        if (ok) {
            #pragma unroll
            for (int i = 0; i < 8; ++i) acc[i] += v[i];
        }
    }

    // combine edge-slot partials across sub-groups
    #pragma unroll
    for (int d = LPE; d < 64; d <<= 1) {
        #pragma unroll
        for (int i = 0; i < 8; ++i) acc[i] += __shfl_xor(acc[i], d, 64);
    }

    if (sub == 0) {
        float dn = dinv[node];
        uint4 o;
        o.x = (unsigned)f2bf(acc[0] * dn) | ((unsigned)f2bf(acc[1] * dn) << 16);
        o.y = (unsigned)f2bf(acc[2] * dn) | ((unsigned)f2bf(acc[3] * dn) << 16);
        o.z = (unsigned)f2bf(acc[4] * dn) | ((unsigned)f2bf(acc[5] * dn) << 16);
        o.w = (unsigned)f2bf(acc[6] * dn) | ((unsigned)f2bf(acc[7] * dn) << 16);
        *reinterpret_cast<uint4*>(out + (size_t)node * F + foff) = o;
    }
}

// ---------------- bf16 MFMA GEMM ----------------
template<bool BN_A, bool SCALE_OUT, bool STATS>
__global__ __launch_bounds__(256) void gemm_bt_k(const unsigned short* __restrict__ A,
                                                 const unsigned short* __restrict__ B,
                                                 unsigned short* __restrict__ C,
                                                 const float* __restrict__ scale,
                                                 const float* __restrict__ shift,
                                                 const float* __restrict__ dinv,
                                                 float* __restrict__ sums,
                                                 float* __restrict__ sqs,
                                                 int n, int K, int M) {
    __shared__ unsigned short As[128][40];
    __shared__ unsigned short Bs[128][40];
    int tid = threadIdx.x;
    int wid = tid >> 6, lane = tid & 63;
    int wr = wid >> 1, wc = wid & 1;
    int row0 = blockIdx.y * 128, col0 = blockIdx.x * 128;

    f32x4 acc[4][4] = {};

    for (int kt = 0; kt < K; kt += 32) {
        int c8 = (tid & 3) * 8;
        float4 sc0, sc1, sh0, sh1;
        if (BN_A) {
            sc0 = *reinterpret_cast<const float4*>(scale + kt + c8);
            sc1 = *reinterpret_cast<const float4*>(scale + kt + c8 + 4);
            sh0 = *reinterpret_cast<const float4*>(shift + kt + c8);
            sh1 = *reinterpret_cast<const float4*>(shift + kt + c8 + 4);
        }
        #pragma unroll
        for (int h = 0; h < 2; ++h) {
            int r = (tid >> 2) + h * 64;
            int gr = row0 + r;
            bf16x8 va = {};
            if (gr < n) va = *reinterpret_cast<const bf16x8*>(A + (size_t)gr * K + kt + c8);
            if (BN_A) {
                #pragma unroll
                for (int t = 0; t < 8; ++t) {
                    float sct = (t < 4) ? (&sc0.x)[t] : (&sc1.x)[t - 4];
                    float sht = (t < 4) ? (&sh0.x)[t] : (&sh1.x)[t - 4];
                    float f = bf2f((unsigned short)va[t]);
                    va[t] = (short)f2bf(fmaxf(f * sct + sht, 0.f));
                }
            }
            *reinterpret_cast<bf16x8*>(&As[r][c8]) = va;
            bf16x8 vb = *reinterpret_cast<const bf16x8*>(B + (size_t)(col0 + r) * K + kt + c8);
            *reinterpret_cast<bf16x8*>(&Bs[r][c8]) = vb;
        }
        __syncthreads();

        bf16x8 af[4], bfr[4];
        int koff = (lane >> 4) * 8;
        #pragma unroll
        for (int f = 0; f < 4; ++f) {
            af[f]  = *reinterpret_cast<const bf16x8*>(&As[wr * 64 + f * 16 + (lane & 15)][koff]);
            bfr[f] = *reinterpret_cast<const bf16x8*>(&Bs[wc * 64 + f * 16 + (lane & 15)][koff]);
        }
        #pragma unroll
        for (int i = 0; i < 4; ++i)
            #pragma unroll
            for (int j = 0; j < 4; ++j)
                acc[i][j] = __builtin_amdgcn_mfma_f32_16x16x32_bf16(af[i], bfr[j], acc[i][j], 0, 0, 0);
        __syncthreads();
    }

    #pragma unroll
    for (int i = 0; i < 4; ++i) {
        #pragma unroll
        for (int q = 0; q < 4; ++q) {
            int gr = row0 + wr * 64 + i * 16 + (lane >> 4) * 4 + q;
            if (gr < n) {
                float dr = SCALE_OUT ? dinv[gr] : 1.0f;
                #pragma unroll
                for (int j = 0; j < 4; ++j) {
                    int gc = col0 + wc * 64 + j * 16 + (lane & 15);
                    C[(size_t)gr * M + gc] = f2bf(acc[i][j][q] * dr);
                }
            }
        }
    }

    if (STATS) {
        #pragma unroll
        for (int j = 0; j < 4; ++j) {
            float s = 0.f, q = 0.f;
            #pragma unroll
            for (int i = 0; i < 4; ++i)
                #pragma unroll
                for (int p = 0; p < 4; ++p) {
                    float v = acc[i][j][p];
                    s += v; q += v * v;
                }
            s += __shfl_xor(s, 16, 64); s += __shfl_xor(s, 32, 64);
            q += __shfl_xor(q, 16, 64); q += __shfl_xor(q, 32, 64);
            if ((lane >> 4) == 0) {
                int gc = col0 + wc * 64 + j * 16 + (lane & 15);
                atomicAdd(&sums[gc], s);
                atomicAdd(&sqs[gc], q);
            }
        }
    }
}

// ---------------- batchnorm stats: uint4 loads, LDS block-reduce, 2F atomics/block ----------------
template<int F>
__global__ __launch_bounds__(256) void bn_stats_k(const unsigned short* __restrict__ in,
                                                  float* __restrict__ stat, int n) {
    constexpr int G   = F / 8;    // threads covering one row (8 bf16 each)
    constexpr int RPP = 256 / G;  // rows per pass
    int g  = threadIdx.x & (G - 1);
    int rl = threadIdx.x / G;

    float s[8] = {}, q[8] = {};
    for (int r = blockIdx.x * RPP + rl; r < n; r += gridDim.x * RPP) {
        uint4 u = *reinterpret_cast<const uint4*>(in + (size_t)r * F + g * 8);
        float v[8]; unpack8(u, v);
        #pragma unroll
        for (int i = 0; i < 8; ++i) { s[i] += v[i]; q[i] += v[i] * v[i]; }
    }

    __shared__ float lds[RPP][F];
    #pragma unroll
    for (int i = 0; i < 8; ++i) lds[rl][g * 8 + i] = s[i];
    __syncthreads();
    if (threadIdx.x < F) {
        float t = 0.f;
        #pragma unroll
        for (int rr = 0; rr < RPP; ++rr) t += lds[rr][threadIdx.x];
        atomicAdd(&stat[threadIdx.x], t);
    }
    __syncthreads();
    #pragma unroll
    for (int i = 0; i < 8; ++i) lds[rl][g * 8 + i] = q[i];
    __syncthreads();
    if (threadIdx.x < F) {
        float t = 0.f;
        #pragma unroll
        for (int rr = 0; rr < RPP; ++rr) t += lds[rr][threadIdx.x];
        atomicAdd(&stat[F + threadIdx.x], t);
    }
}

__global__ void bn_finalize_k(const float* __restrict__ stat,
                              const float* __restrict__ g, const float* __restrict__ be,
                              float* __restrict__ scale, float* __restrict__ shift,
                              int F, float invn) {
    int f = blockIdx.x * blockDim.x + threadIdx.x;
    if (f >= F) return;
    float mean = stat[f] * invn;
    float var  = stat[F + f] * invn - mean * mean;
    float rstd = rsqrtf(var + 1e-5f);
    float sc = g[f] * rstd;
    scale[f] = sc;
    shift[f] = be[f] - mean * sc;
}

// ---------------- pooling ----------------
__global__ void bounds_k(const int* __restrict__ batch, int* __restrict__ start, int n) {
    int i = blockIdx.x * blockDim.x + threadIdx.x;
    if (i >= n) return;
    int b = batch[i];
    if (i == 0) {
        for (int g = 0; g <= b; ++g) start[g] = 0;
    } else {
        int pb = batch[i - 1];
        for (int g = pb + 1; g <= b; ++g) start[g] = i;
    }
    if (i == n - 1) {
        for (int g = b + 1; g <= NGRAPHS; ++g) start[g] = n;
    }
}

__global__ __launch_bounds__(256) void pool_part_k(const unsigned short* __restrict__ a,
                                                   const int* __restrict__ start,
                                                   const float* __restrict__ scale,
                                                   const float* __restrict__ shift,
                                                   float* __restrict__ partial) {
    int g = blockIdx.x, q = blockIdx.y;
    int s = start[g], e = start[g + 1];
    int nr = e - s;
    int c0 = s + (nr * q) / 4, c1 = s + (nr * (q + 1)) / 4;
    int tf = threadIdx.x & 15, tr = threadIdx.x >> 4;

    float sc[8], sh[8];
    #pragma unroll
    for (int i = 0; i < 8; ++i) { sc[i] = scale[tf * 8 + i]; sh[i] = shift[tf * 8 + i]; }

    float acc[8] = {};
    for (int r = c0 + tr; r < c1; r += 16) {
        uint4 u = *reinterpret_cast<const uint4*>(a + (size_t)r * 128 + tf * 8);
        float v[8]; unpack8(u, v);
        #pragma unroll
        for (int i = 0; i < 8; ++i) acc[i] += fmaxf(v[i] * sc[i] + sh[i], 0.f);
    }

    __shared__ float red[16][128];
    #pragma unroll
    for (int i = 0; i < 8; ++i) red[tr][tf * 8 + i] = acc[i];
    __syncthreads();
    int f = threadIdx.x;
    if (f < 128) {
        float s2 = 0.f;
        #pragma unroll
        for (int t = 0; t < 16; ++t) s2 += red[t][f];
        partial[((size_t)(g * 4 + q)) * 128 + f] = s2;
    }
}

__global__ void final_out_k(const float* __restrict__ partial, const int* __restrict__ start,
                            const float* __restrict__ Wo, const float* __restrict__ bo,
                            float* __restrict__ out) {
    int idx = blockIdx.x * blockDim.x + threadIdx.x;
    if (idx >= NGRAPHS * 10) return;
    int g = idx / 10, c = idx - g * 10;
    float cntf = (float)(start[g + 1] - start[g]);
    float inv = 1.0f / fmaxf(cntf, 1.0f);
    float s = bo[c];
    for (int k = 0; k < 128; ++k) {
        float pk = partial[(size_t)(g * 4 + 0) * 128 + k] + partial[(size_t)(g * 4 + 1) * 128 + k]
                 + partial[(size_t)(g * 4 + 2) * 128 + k] + partial[(size_t)(g * 4 + 3) * 128 + k];
        s += pk * inv * Wo[k * 10 + c];
    }
    out[idx] = s;
}

// ---------------- driver ----------------
extern "C" void kernel_launch(void* const* d_in, const int* in_sizes, int n_in,
                              void* d_out, int out_size, void* d_ws, size_t ws_size,
                              hipStream_t stream) {
    const float* x   = (const float*)d_in[0];
    const int*   ei  = (const int*)d_in[1];
    const int*   bat = (const int*)d_in[2];
    const float* W1  = (const float*)d_in[3];
    const float* g1  = (const float*)d_in[5];
    const float* be1 = (const float*)d_in[6];
    const float* W2  = (const float*)d_in[7];
    const float* g2  = (const float*)d_in[9];
    const float* be2 = (const float*)d_in[10];
    const float* W3  = (const float*)d_in[11];
    const float* g3  = (const float*)d_in[13];
    const float* be3 = (const float*)d_in[14];
    const float* Wo  = (const float*)d_in[15];
    const float* bo  = (const float*)d_in[16];
    float* out = (float*)d_out;

    const int n  = in_sizes[2];       // 50000
    const int ne = in_sizes[1] / 2;   // 800000
    const int* row = ei;
    const int* col = ei + ne;
    const int NB = (n + 1023) / 1024; // scan blocks

    char* base = (char*)d_ws;
    size_t o = 0;
    auto alloc = [&](size_t bytes) -> char* {
        char* p = base + o;
        o += (bytes + 255) & ~(size_t)255;
        return p;
    };
    // zero-init region: cnt | fill | stat1 | stat2 | stat3 (single memset)
    int*   cntfill = (int*)alloc((size_t)2 * n * 4);
    int*   cnt  = cntfill;
    int*   fill = cntfill + n;
    float* statall = (float*)alloc((size_t)3 * 1024 * 4);
    float* stat1 = statall;            // 512 sums | 512 sqs
    float* stat2 = statall + 1024;     // 256 sums | 256 sqs
    float* stat3 = statall + 2048;     // 128 sums | 128 sqs
    size_t zspan = (size_t)((char*)(statall + 3 * 1024) - (char*)cntfill);

    int*   offs  = (int*)alloc(n * 4);
    int*   bsum  = (int*)alloc(256 * 4);
    float* dinv  = (float*)alloc(n * 4);
    int*   start = (int*)alloc((NGRAPHS + 1) * 4);
    float* scale = (float*)alloc(512 * 4);
    float* shift = (float*)alloc(512 * 4);
    float* partial = (float*)alloc((size_t)NGRAPHS * 4 * 128 * 4);
    int*   csr_row = (int*)alloc((size_t)ne * 4);
    unsigned short* Wt1 = (unsigned short*)alloc((size_t)128 * 512 * 2);
    unsigned short* Wt2 = (unsigned short*)alloc((size_t)512 * 256 * 2);
    unsigned short* Wt3 = (unsigned short*)alloc((size_t)256 * 128 * 2);
    unsigned short* xs_bf  = (unsigned short*)alloc((size_t)n * 128 * 2);
    unsigned short* ax_bf  = (unsigned short*)alloc((size_t)n * 128 * 2);
    unsigned short* h1_bf  = (unsigned short*)alloc((size_t)n * 512 * 2);
    unsigned short* t2s_bf = (unsigned short*)alloc((size_t)n * 256 * 2);
    unsigned short* a2_bf  = (unsigned short*)alloc((size_t)n * 256 * 2);
    unsigned short* t3s_bf = (unsigned short*)alloc((size_t)n * 128 * 2);
    unsigned short* a3_bf  = (unsigned short*)alloc((size_t)n * 128 * 2);

    // ---- graph preprocessing ----
    hipMemsetAsync(cntfill, 0, zspan, stream);
    deg_count_k<<<(ne + 255) / 256, 256, 0, stream>>>(col, cnt, ne);
    scan1_k<<<NB, 256, 0, stream>>>(cnt, offs, bsum, dinv, n);
    scan2_k<<<1, 256, 0, stream>>>(bsum, NB);
    scan3_k<<<NB, 256, 0, stream>>>(offs, bsum, n);
    scatter_k<<<(ne + 255) / 256, 256, 0, stream>>>(row, col, offs, fill, csr_row, ne);
    bounds_k<<<(n + 255) / 256, 256, 0, stream>>>(bat, start, n);

    // ---- conversions ----
    cvt_scale_k<<<(unsigned)(((long long)n * 32 + 255) / 256), 256, 0, stream>>>(x, dinv, xs_bf, n);
    wtrans_all_k<<<896, 256, 0, stream>>>(W1, W2, W3, Wt1, Wt2, Wt3);

    // ---- Layer 1: agg(xs)[128] -> @W1 [512] (+fused column stats) ----
    agg_s_k<2><<<(n + 3) / 4, 256, 0, stream>>>(xs_bf, offs, cnt, csr_row, dinv, ax_bf, n);
    gemm_bt_k<false, false, true><<<dim3(4, (n + 127) / 128), 256, 0, stream>>>(
        ax_bf, Wt1, h1_bf, nullptr, nullptr, nullptr, stat1, stat1 + 512, n, 128, 512);
    bn_finalize_k<<<2, 256, 0, stream>>>(stat1, g1, be1, scale, shift, 512, 1.0f / n);

    // ---- Layer 2: bn+relu(h1) @ W2 [256] (output prescaled) -> agg ----
    gemm_bt_k<true, true, false><<<dim3(2, (n + 127) / 128), 256, 0, stream>>>(
        h1_bf, Wt2, t2s_bf, scale, shift, dinv, nullptr, nullptr, n, 512, 256);
    agg_s_k<4><<<(n + 3) / 4, 256, 0, stream>>>(t2s_bf, offs, cnt, csr_row, dinv, a2_bf, n);
    bn_stats_k<256><<<1024, 256, 0, stream>>>(a2_bf, stat2, n);
    bn_finalize_k<<<1, 256, 0, stream>>>(stat2, g2, be2, scale, shift, 256, 1.0f / n);

    // ---- Layer 3: bn+relu(a2) @ W3 [128] (output prescaled) -> agg ----
    gemm_bt_k<true, true, false><<<dim3(1, (n + 127) / 128), 256, 0, stream>>>(
        a2_bf, Wt3, t3s_bf, scale, shift, dinv, nullptr, nullptr, n, 256, 128);
    agg_s_k<2><<<(n + 3) / 4, 256, 0, stream>>>(t3s_bf, offs, cnt, csr_row, dinv, a3_bf, n);
    bn_stats_k<128><<<1024, 256, 0, stream>>>(a3_bf, stat3, n);
    bn_finalize_k<<<1, 256, 0, stream>>>(stat3, g3, be3, scale, shift, 128, 1.0f / n);

    // ---- pool (fused BN+ReLU) + output ----
    pool_part_k<<<dim3(NGRAPHS, 4), 256, 0, stream>>>(a3_bf, start, scale, shift, partial);
    final_out_k<<<3, 256, 0, stream>>>(partial, start, Wo, bo, out);
}